// Round 24
// baseline (278.198 us; speedup 1.0000x reference)
//
#include <hip/hip_runtime.h>
#include <hip/hip_bf16.h>

// Problem constants
#define NN 25600      // D*H*W = 16*40*40
#define CC 96
#define NHh 4
#define HDd 24
#define SSLOT 2457600 // NN*CC floats per workspace slot
#define WP 269568     // padded conv weight tensor: 27*96*104 ushorts

typedef unsigned short ushort_t;
typedef float f32x4 __attribute__((ext_vector_type(4)));
typedef short s16x8 __attribute__((ext_vector_type(8)));
typedef _Float16 f16;
typedef f16 h2v __attribute__((ext_vector_type(2)));

__device__ __forceinline__ float LD(const void* p, int i){
  return ((const float*)p)[i];
}
__device__ __forceinline__ float b2f(ushort_t u){ return __uint_as_float(((unsigned)u)<<16); }
__device__ __forceinline__ ushort_t f2b(float f){
  unsigned u = __float_as_uint(f);
  unsigned r = (u + 0x7fffu + ((u>>16)&1u))>>16;
  return (ushort_t)r;
}
__device__ __forceinline__ ushort_t f2h(float f){
  f16 hv = (f16)f;
  return *reinterpret_cast<ushort_t*>(&hv);
}
__device__ __forceinline__ float fdot2(h2v a, h2v b, float c){
#if __has_builtin(__builtin_amdgcn_fdot2)
  return __builtin_amdgcn_fdot2(a, b, c, false);
#else
  return c + (float)a[0]*(float)b[0] + (float)a[1]*(float)b[1];
#endif
}
__device__ __forceinline__ void gl_lds16(const void* g, const void* l){
  __builtin_amdgcn_global_load_lds(
      (const __attribute__((address_space(1))) unsigned*)g,
      (__attribute__((address_space(3))) unsigned*)l, 16, 0, 0);
}

#define NEGINF (-3.0e38f)

// ---------------- MEGA prologue: prepall | rpiT | ln | tab in one launch ------------
__global__ __launch_bounds__(256) void k_mega(
    const void* w0, const void* w1, const void* w2, const void* w3,
    const void* wq, const void* wsr, const void* w8,
    const void* o1w, const void* o1b, const void* o2w, const void* o2b,
    const void* b0, const void* b1, const void* b2bn, const void* b3,
    const void* ltok,
    ushort_t* __restrict__ WB2, ushort_t* __restrict__ WQH,
    ushort_t* __restrict__ WSH, ushort_t* __restrict__ W8H,
    ushort_t* __restrict__ WE, float* __restrict__ EB,
    float* __restrict__ BNS, ushort_t* __restrict__ LTOKT,
    float* __restrict__ ZB,
    const int* __restrict__ rpi, int* __restrict__ rpiT,
    const void* __restrict__ x, const void* __restrict__ nw,
    const void* __restrict__ nb, ushort_t* __restrict__ XNH,
    const void* __restrict__ rct, const void* __restrict__ w1t,
    const void* __restrict__ b1t, const void* __restrict__ w2t,
    const void* __restrict__ b2t, float* __restrict__ TAB)
{
  __shared__ __align__(16) char SMEM[15400];
  int b = blockIdx.x, tid = threadIdx.x;
  if(b < 4212){
    int e = b*256 + tid;
    {
      int t = e/WP, r = e%WP;
      int tap = r/9984, r2 = r%9984, o = r2/104, p = r2%104;
      const void* w = (t==0)? w0 : (t==1)? w1 : (t==2)? w2 : w3;
      WB2[e] = (p<96)? f2b(LD(w, (o*96+p)*27 + tap)) : (ushort_t)0;
    }
    if(e < 36864) WQH[e] = f2b(LD(wq,e));
    if(e < 9216){ WSH[e] = f2b(LD(wsr,e)); W8H[e] = f2b(LD(w8,e)); }
    if(e < 96*192){
      int o = e/192, c2 = e%192;
      float v = 0.f;
      if(o < 48 && c2 < 96)        v = LD(o1w, o*96 + c2);
      else if(o >= 48 && c2 >= 96) v = LD(o2w, (o-48)*96 + (c2-96));
      WE[e] = f2b(v);
      if(c2 == 0) EB[o] = (o<48)? LD(o1b,o) : LD(o2b,o-48);
    }
    if(e < 384){
      int t = e/96, o = e%96;
      const void* bn = (t==0)? b0 : (t==1)? b1 : (t==2)? b2bn : b3;
      float g=LD(bn,o), bb=LD(bn,96+o), mu=LD(bn,192+o), var=LD(bn,288+o);
      float s = g*rsqrtf(var+1e-5f);
      BNS[t*192+o] = s;
      BNS[t*192+96+o] = bb - mu*s;
    }
    if(e < 4096){
      int h = e/1024, r = e%1024, kk = r/32, d = r%32;
      float v = (d<24 && kk<27)? LD(ltok, (h*24+d)*27 + kk) : 0.f;
      LTOKT[e] = f2b(v);
    }
    if(e < 8) ZB[e] = 0.f;
  } else if(b < 4612){
    int* T = (int*)SMEM;                 // [50][65]
    int n0 = (b-4212)*64;
    for(int f=tid; f<3200; f+=256){
      int nl = f/50, p = f%50;
      T[p*65+nl] = rpi[n0*50 + f];
    }
    __syncthreads();
    for(int f=tid; f<3200; f+=256){
      int p = f>>6, nl = f&63;
      rpiT[(size_t)p*NN + n0 + nl] = T[p*65+nl];
    }
  } else if(b < 5012){
    float* reds  = (float*)SMEM;         // [4][64]
    float* redss = reds + 256;           // [4][64]
    ushort_t* OUT = (ushort_t*)(redss + 256); // [64][100]
    int bx = b - 4612;
    int nl = tid&63, cg = tid>>6;
    int n = bx*64 + nl;
    float v[24]; float s=0.f, ss=0.f;
    #pragma unroll
    for(int i=0;i<24;i++){
      float t = LD(x, (cg*24+i)*NN + n) + 1.0f;
      v[i]=t; s+=t; ss+=t*t;
    }
    reds[cg*64+nl]=s; redss[cg*64+nl]=ss;
    __syncthreads();
    float S  = reds[nl]+reds[64+nl]+reds[128+nl]+reds[192+nl];
    float SS = redss[nl]+redss[64+nl]+redss[128+nl]+redss[192+nl];
    float mu = S*(1.0f/CC);
    float inv = rsqrtf(SS*(1.0f/CC) - mu*mu + 1e-5f);
    #pragma unroll
    for(int i=0;i<24;i++){
      int c = cg*24+i;
      OUT[nl*100+c] = f2b((v[i]-mu)*inv*LD(nw,c) + LD(nb,c));
    }
    __syncthreads();
    for(int f=tid; f<3072; f+=256){
      int r = f/48, dp = f%48;
      unsigned pk = (unsigned)OUT[r*100+dp*2] | ((unsigned)OUT[r*100+dp*2+1]<<16);
      *reinterpret_cast<unsigned*>(XNH + (size_t)(bx*64+r)*96 + dp*2) = pk;
    }
  } else {
    float* red = (float*)SMEM;           // [16]
    int tt = b - 5012, j = tid;
    float r0=LD(rct,tt*3), r1=LD(rct,tt*3+1), r2=LD(rct,tt*3+2);
    float hA = r0*LD(w1t,j*3) + r1*LD(w1t,j*3+1) + r2*LD(w1t,j*3+2) + LD(b1t,j);
    hA = fmaxf(hA, 0.f);
    int j2 = j + 256;
    float hB = r0*LD(w1t,j2*3) + r1*LD(w1t,j2*3+1) + r2*LD(w1t,j2*3+2) + LD(b1t,j2);
    hB = fmaxf(hB, 0.f);
    int lane=j&63, wid=j>>6;
    for(int h=0;h<4;h++){
      float v = hA*LD(w2t, h*512+j) + hB*LD(w2t, h*512+j2);
      #pragma unroll
      for(int off=32;off;off>>=1) v += __shfl_down(v, off);
      if(lane==0) red[wid*4+h]=v;
    }
    __syncthreads();
    if(j<4){
      float s = red[j] + red[4+j] + red[8+j] + red[12+j];
      TAB[tt*4+j] = s + LD(b2t,j);
    }
  }
}

// ---------------- K2+K4 fused: qkvv (y=0,1) and sr+gelu (y=2) MFMA GEMMs -----------
__global__ __launch_bounds__(256,2) void k_qkvsr(
    const ushort_t* __restrict__ XNH, const ushort_t* __restrict__ WQH,
    const ushort_t* __restrict__ WSH, const void* __restrict__ srb,
    float* __restrict__ out, ushort_t* __restrict__ KH,
    ushort_t* __restrict__ VH, float* __restrict__ XP2){
  int tid=threadIdx.x, w=tid>>6, lane=tid&63, lan=lane&15, grp=lane>>4;
  int n = blockIdx.x*64 + w*16 + lan;
  const ushort_t* bp = XNH + n*96;
  if(blockIdx.y < 2){
    int ybase = blockIdx.y*192;
    f32x4 acc[12];
    #pragma unroll
    for(int mt=0;mt<12;mt++) acc[mt] = (f32x4)(0.f);
    #pragma unroll
    for(int s=0;s<3;s++){
      s16x8 b = *reinterpret_cast<const s16x8*>(bp + s*32 + grp*8);
      #pragma unroll
      for(int mt=0;mt<12;mt++){
        s16x8 a = *reinterpret_cast<const s16x8*>(WQH + (ybase+mt*16+lan)*96 + s*32 + grp*8);
        acc[mt] = __builtin_amdgcn_mfma_f32_16x16x32_bf16(a, b, acc[mt], 0,0,0);
      }
    }
    #pragma unroll
    for(int mt=0;mt<12;mt++){
      int o0 = ybase + mt*16 + grp*4;
      int sl = o0/96, rr = o0%96, h = rr/24, dd = rr%24;
      f32x4 v = acc[mt];
      if(sl == 3){
        ushort4 pk = { f2h(v[0]), f2h(v[1]), f2h(v[2]), f2h(v[3]) };
        *reinterpret_cast<ushort4*>(VH + ((size_t)h*NN+n)*24 + dd) = pk;
      } else {
        *reinterpret_cast<float4*>(out + sl*SSLOT + ((size_t)h*NN+n)*24 + dd) =
            (float4){v[0],v[1],v[2],v[3]};
        if(sl == 1){
          ushort4 pk = { f2h(v[0]), f2h(v[1]), f2h(v[2]), f2h(v[3]) };
          *reinterpret_cast<ushort4*>(KH + ((size_t)h*NN+n)*24 + dd) = pk;
        }
      }
    }
  } else {
    f32x4 acc[6];
    #pragma unroll
    for(int mt=0;mt<6;mt++) acc[mt] = (f32x4)(0.f);
    #pragma unroll
    for(int s=0;s<3;s++){
      s16x8 b = *reinterpret_cast<const s16x8*>(bp + s*32 + grp*8);
      #pragma unroll
      for(int mt=0;mt<6;mt++){
        s16x8 a = *reinterpret_cast<const s16x8*>(WSH + (mt*16+lan)*96 + s*32 + grp*8);
        acc[mt] = __builtin_amdgcn_mfma_f32_16x16x32_bf16(a, b, acc[mt], 0,0,0);
      }
    }
    #pragma unroll
    for(int mt=0;mt<6;mt++){
      #pragma unroll
      for(int r=0;r<4;r++){
        int o = mt*16 + grp*4 + r;
        float y = acc[mt][r] + LD(srb,o);
        y = 0.5f*y*(1.0f + erff(y*0.70710678118f));
        XP2[o*NN+n] = y;
      }
    }
  }
}

// ---------------- MID1: qsltm (b<400) | pool x4 (b>=400) ----------------
__global__ __launch_bounds__(256) void k_mid1(
    const float* __restrict__ Q, const void* __restrict__ temp,
    const void* __restrict__ sls, const void* __restrict__ qe,
    const ushort_t* __restrict__ LTOKT, const void* __restrict__ lbias,
    float* __restrict__ QS, ushort_t* __restrict__ LTH,
    const float* __restrict__ XP2, float* __restrict__ pooled)
{
  __shared__ ushort_t QL[4][64][32];   // 16 KB
  int b = blockIdx.x, tid = threadIdx.x;
  if(b < 400){
    int h = tid>>6, nl = tid&63;
    int n0 = b*64, n = n0 + nl;
    const float* qr = Q + ((size_t)h*NN+n)*24;
    float qv[24]; float ssum=0.f;
    #pragma unroll
    for(int d=0;d<24;d++){ qv[d]=qr[d]; ssum+=qv[d]*qv[d]; }
    float inv = 1.0f/fmaxf(sqrtf(ssum), 1e-12f);
    float t = LD(temp,h);
    float sp = log1pf(expf(t)) * LD(sls,0);
    float* qs = QS + ((size_t)h*NN+n)*24;
    #pragma unroll
    for(int d=0;d<24;d+=2){
      float q0 = qv[d]*inv, q1 = qv[d+1]*inv;
      unsigned pk = (unsigned)f2b(q0) | ((unsigned)f2b(q1)<<16);
      *reinterpret_cast<unsigned*>(&QL[h][nl][d]) = pk;
      qs[d]   = (q0 + LD(qe, h*24+d))*sp;
      qs[d+1] = (q1 + LD(qe, h*24+d+1))*sp;
    }
    *reinterpret_cast<unsigned*>(&QL[h][nl][24]) = 0;
    *reinterpret_cast<unsigned*>(&QL[h][nl][26]) = 0;
    *reinterpret_cast<unsigned*>(&QL[h][nl][28]) = 0;
    *reinterpret_cast<unsigned*>(&QL[h][nl][30]) = 0;
    __syncthreads();
    int lane=tid&63, lan=lane&15, grp=lane>>4;
    f32x4 acc[4][2];
    #pragma unroll
    for(int j=0;j<4;j++)
      #pragma unroll
      for(int tt=0;tt<2;tt++) acc[j][tt] = (f32x4)(0.f);
    #pragma unroll
    for(int j=0;j<4;j++){
      s16x8 bb = *reinterpret_cast<const s16x8*>(&QL[h][j*16+lan][grp*8]);
      #pragma unroll
      for(int tt=0;tt<2;tt++){
        s16x8 a = *reinterpret_cast<const s16x8*>(LTOKT + h*1024 + (tt*16+lan)*32 + grp*8);
        acc[j][tt] = __builtin_amdgcn_mfma_f32_16x16x32_bf16(a, bb, acc[j][tt], 0,0,0);
      }
    }
    #pragma unroll
    for(int j=0;j<4;j++){
      int nn = n0 + j*16 + lan;
      #pragma unroll
      for(int tt=0;tt<2;tt++){
        int k0 = tt*16 + grp*4;
        if(k0 < 28){
          ushort4 pk;
          ushort_t* pp = reinterpret_cast<ushort_t*>(&pk);
          #pragma unroll
          for(int r=0;r<4;r++){
            int k = k0+r;
            float v = acc[j][tt][r] + ((k<27)? LD(lbias, h*27+k) : 0.f);
            pp[r] = f2h(v);
          }
          *reinterpret_cast<ushort4*>(LTH + ((size_t)h*NN+nn)*28 + k0) = pk;
        }
      }
    }
  } else {
    int w = tid>>6, lane = tid&63;
    int pb = (b-400)*4 + w;              // [0,4800)
    int c = pb % CC, p = pb / CC;
    int ph = p/10, pw = (p%10)/2, pd = p%2;
    float s = 0.f;
    for(int t=lane; t<512; t+=64){
      int i=t>>6, j=(t>>3)&7, k=t&7;
      int m = (ph*8+i)*640 + (pw*8+j)*16 + (pd*8+k);
      s += XP2[c*NN+m];
    }
    #pragma unroll
    for(int off=32;off;off>>=1) s += __shfl_down(s, off);
    if(lane==0) pooled[p*CC+c] = s*(1.0f/512.0f);
  }
}

// ---------------- MID2: LN(pooled) + kv + inlined kpn -> KPNH/VPH f16 ---------------
__global__ void k_mid2(const float* __restrict__ pooled, const void* __restrict__ ew,
                       const void* __restrict__ eb, const void* __restrict__ wkv,
                       ushort_t* __restrict__ KPNH, ushort_t* __restrict__ VPH){
  __shared__ float row[96], lnr[96], st[2], kk[96];
  int p = blockIdx.x, t = threadIdx.x;
  if(t<96) row[t] = pooled[p*96+t];
  __syncthreads();
  if(t==0){
    float s=0.f, ss=0.f;
    for(int c=0;c<96;c++){ float v=row[c]; s+=v; ss+=v*v; }
    float mu=s*(1.0f/96.0f);
    float var=ss*(1.0f/96.0f)-mu*mu;
    st[0]=mu; st[1]=rsqrtf(var+1e-5f);
  }
  __syncthreads();
  if(t<96) lnr[t] = (row[t]-st[0])*st[1]*LD(ew,t) + LD(eb,t);
  __syncthreads();
  if(t<192){
    float a=0.f;
    for(int c=0;c<96;c++) a += LD(wkv, t*96+c)*lnr[c];
    int g=t/24, d=t%24;
    if(g<4) kk[t]=a;
    else    VPH[((g-4)*50+p)*24+d] = f2h(a);
  }
  __syncthreads();
  if(t<96){
    int g=t/24, d=t%24;
    float ss=0.f;
    #pragma unroll
    for(int e=0;e<24;e++){ float v=kk[g*24+e]; ss+=v*v; }
    float inv = 1.0f/fmaxf(sqrtf(ss),1e-12f);
    KPNH[((g*50+p)*24)+d] = f2h(kk[t]*inv);
  }
}

// ---------------- BIG: cascore3 FIRST (b<64) | attn6 (b in [64,464)) ----------------
__global__ __launch_bounds__(512) void k_big(
    const float* __restrict__ QS, const ushort_t* __restrict__ KH,
    const ushort_t* __restrict__ VH,
    const ushort_t* __restrict__ KPNH, const ushort_t* __restrict__ VPH,
    const float* __restrict__ TAB, const int* __restrict__ rpiT,
    const void* __restrict__ rbl, const ushort_t* __restrict__ LTH,
    ushort_t* __restrict__ XH,
    const float* __restrict__ Q, const float* __restrict__ K,
    float* __restrict__ PAR)
{
  __shared__ ushort_t KVH[2][600*26];   // 62.4 KB (aliased by cascore3's reduce)
  int bb = blockIdx.x, tid = threadIdx.x;
  if(bb >= 64){
    int bb2 = bb - 64;
    int tile = bb2 % 100, h = bb2 / 100;
    int g = tile/25, sp = tile%25, hg = sp/5, wg = sp%5;
    int role = tid>>8, q = tid & 255;
    int wq = q>>6, l = q&63;
    int hy = l>>3, wx = l&7;
    int d0 = g*4 + wq;
    int h0 = hg*8+hy, w0 = wg*8+wx;
    int n = d0*1600 + h0*40 + w0;

    const ushort_t* KHh = KH + (size_t)h*NN*24;
    const ushort_t* VHh = VH + (size_t)h*NN*24;
    for(int f=tid; f<3600; f+=512){
      int t = f/1800, rem = f%1800, row = rem/3, qq = rem%3;
      int dr = row/100, yr = (row%100)/10, xr = row%10;
      int zc = min(max(g*4+dr-1,0),15), yc = min(max(hg*8+yr-1,0),39), xc = min(max(wg*8+xr-1,0),39);
      const ushort_t* src = (t? VHh : KHh) + (size_t)(zc*1600+yc*40+xc)*24 + qq*8;
      const unsigned* s32 = reinterpret_cast<const unsigned*>(src);
      unsigned a0=s32[0], a1=s32[1], a2=s32[2], a3=s32[3];
      unsigned* d32 = reinterpret_cast<unsigned*>(&KVH[t][row*26 + qq*8]);
      d32[0]=a0; d32[1]=a1; d32[2]=a2; d32[3]=a3;
    }

    h2v qp[12];
    {
      const float* qsp = QS + ((size_t)h*NN+n)*24;
      #pragma unroll
      for(int d=0; d<24; d+=4){
        float4 a = *reinterpret_cast<const float4*>(qsp+d);
        qp[d/2]   = (h2v){ (f16)a.x, (f16)a.y };
        qp[d/2+1] = (h2v){ (f16)a.z, (f16)a.w };
      }
    }
    __syncthreads();

    float m_r, s_r;
    h2v accA[12], accT[12];
    #pragma unroll
    for(int j=0;j<12;j++){ accA[j]=(h2v){(f16)0.f,(f16)0.f}; accT[j]=(h2v){(f16)0.f,(f16)0.f}; }

    const h2v* kph = reinterpret_cast<const h2v*>(KPNH) + (size_t)h*50*12;
    const h2v* vph = reinterpret_cast<const h2v*>(VPH)  + (size_t)h*50*12;

    if(role==0){
      float av[39]; unsigned okm=0;
      #pragma unroll
      for(int k=0;k<27;k++){
        int kz=k/9, ky=(k%9)/3, kx=k%3;
        bool ok = (unsigned)(d0+kz-1)<16u && (unsigned)(h0+ky-1)<40u && (unsigned)(w0+kx-1)<40u;
        float sc = NEGINF;
        if(ok){
          okm |= 1u<<k;
          const h2v* kr = reinterpret_cast<const h2v*>(
              &KVH[0][((wq+kz)*100 + (hy+ky)*10 + (wx+kx))*26]);
          sc = LD(rbl, h*27+k);
          #pragma unroll
          for(int j=0;j<12;j++) sc = fdot2(kr[j], qp[j], sc);
        }
        av[k]=sc;
      }
      #pragma unroll
      for(int p=0;p<12;p++){
        float sc = TAB[rpiT[(size_t)p*NN+n]*4 + h];
        const h2v* kr = kph + p*12;
        #pragma unroll
        for(int j=0;j<12;j++) sc = fdot2(kr[j], qp[j], sc);
        av[27+p]=sc;
      }
      float m = av[0];
      #pragma unroll
      for(int k=1;k<39;k++) m = fmaxf(m, av[k]);
      const f16* ltp = reinterpret_cast<const f16*>(LTH) + ((size_t)h*NN+n)*28;
      float s = 0.f;
      #pragma unroll
      for(int k=0;k<27;k++){
        if(okm>>k & 1u){
          int kz=k/9, ky=(k%9)/3, kx=k%3;
          float e = __expf(av[k]-m);
          s += e;
          float ltv = (float)ltp[k];
          h2v we = { (f16)e, (f16)e };
          h2v wt = { (f16)ltv, (f16)ltv };
          const h2v* vr = reinterpret_cast<const h2v*>(
              &KVH[1][((wq+kz)*100 + (hy+ky)*10 + (wx+kx))*26]);
          #pragma unroll
          for(int j=0;j<12;j++){
            accA[j] = vr[j]*we + accA[j];
            accT[j] = vr[j]*wt + accT[j];
          }
        }
      }
      #pragma unroll
      for(int p=0;p<12;p++){
        float e = __expf(av[27+p]-m);
        s += e;
        h2v we = { (f16)e, (f16)e };
        const h2v* vr = vph + p*12;
        #pragma unroll
        for(int j=0;j<12;j++) accA[j] = vr[j]*we + accA[j];
      }
      m_r = m; s_r = s;
    } else {
      float av[38];
      #pragma unroll
      for(int p=0;p<38;p++){
        int pp = p+12;
        float sc = TAB[rpiT[(size_t)pp*NN+n]*4 + h];
        const h2v* kr = kph + pp*12;
        #pragma unroll
        for(int j=0;j<12;j++) sc = fdot2(kr[j], qp[j], sc);
        av[p]=sc;
      }
      float m = av[0];
      #pragma unroll
      for(int p=1;p<38;p++) m = fmaxf(m, av[p]);
      float s = 0.f;
      #pragma unroll
      for(int p=0;p<38;p++){
        float e = __expf(av[p]-m);
        s += e;
        h2v we = { (f16)e, (f16)e };
        const h2v* vr = vph + (p+12)*12;
        #pragma unroll
        for(int j=0;j<12;j++) accA[j] = vr[j]*we + accA[j];
      }
      m_r = m; s_r = s;
    }
    __syncthreads();

    float* PP = (float*)&KVH[0][0];
    if(role==1){
      PP[q*15+0] = m_r;
      PP[q*15+1] = s_r;
      #pragma unroll
      for(int j=0;j<12;j++){
        h2v a = accA[j];
        PP[q*15+2+j] = __uint_as_float(*reinterpret_cast<unsigned*>(&a));
      }
    }
    __syncthreads();

    float* TRF = (float*)&KVH[0][0] + 4096;
    if(role==0){
      float mp = PP[q*15+0], sp2 = PP[q*15+1];
      float m = fmaxf(m_r, mp);
      float a = __expf(m_r - m), b = __expf(mp - m);
      float inv = 1.0f/(a*s_r + b*sp2);
      #pragma unroll
      for(int j=0;j<12;j++){
        unsigned pb = __float_as_uint(PP[q*15+2+j]);
        h2v ap = *reinterpret_cast<h2v*>(&pb);
        float v0 = (a*(float)accA[j][0] + b*(float)ap[0])*inv + (float)accT[j][0];
        float v1 = (a*(float)accA[j][1] + b*(float)ap[1])*inv + (float)accT[j][1];
        TRF[q*25 + 2*j]   = v0;
        TRF[q*25 + 2*j+1] = v1;
      }
    }
    __syncthreads();

    for(int f=tid; f<3072; f+=512){
      int q2 = f/12, dp = f%12;
      int w2 = q2>>6, l2 = q2&63;
      int n2 = (g*4+w2)*1600 + (hg*8+(l2>>3))*40 + (wg*8+(l2&7));
      float v0 = TRF[q2*25+dp*2], v1 = TRF[q2*25+dp*2+1];
      unsigned pk = (unsigned)f2b(v0) | ((unsigned)f2b(v1)<<16);
      *reinterpret_cast<unsigned*>(XH + (size_t)n2*192 + h*24 + dp*2) = pk;
    }
  } else {
    // cascore3: register-tiled QtK. 64 blocks: (h, chunk16). Q,K read exactly once.
    float* WRED = (float*)&KVH[0][0];    // [8 waves][36 lanes][25] = 28.8 KB
    int b2 = bb;                         // [0,64)
    int h = b2 >> 4, chunk = b2 & 15;
    int wv = tid >> 6, lane = tid & 63;
    int n0 = chunk*1600 + wv*200;
    const float* Qh = Q + (size_t)h*NN*24;
    const float* Kh = K + (size_t)h*NN*24;
    int r = lane/6, cgl = lane%6;
    bool act = lane < 36;
    int d1 = r*4, d2 = cgl*4;
    float accm[4][4];
    #pragma unroll
    for(int i=0;i<4;i++)
      #pragma unroll
      for(int j=0;j<4;j++) accm[i][j]=0.f;
    float qss4[4] = {0.f,0.f,0.f,0.f}, kss4[4] = {0.f,0.f,0.f,0.f};
    if(act){
      #pragma unroll 4
      for(int i=0;i<200;i++){
        int n = n0 + i;
        float4 q4 = *reinterpret_cast<const float4*>(Qh + (size_t)n*24 + d1);
        float4 k4 = *reinterpret_cast<const float4*>(Kh + (size_t)n*24 + d2);
        float qa[4] = {q4.x,q4.y,q4.z,q4.w};
        float ka[4] = {k4.x,k4.y,k4.z,k4.w};
        #pragma unroll
        for(int i2=0;i2<4;i2++)
          #pragma unroll
          for(int j=0;j<4;j++) accm[i2][j] += qa[i2]*ka[j];
        #pragma unroll
        for(int e=0;e<4;e++){ qss4[e]+=qa[e]*qa[e]; kss4[e]+=ka[e]*ka[e]; }
      }
      float* wp = WRED + (wv*36 + lane)*25;
      #pragma unroll
      for(int i=0;i<4;i++)
        #pragma unroll
        for(int j=0;j<4;j++) wp[i*4+j] = accm[i][j];
      if(r == cgl){
        #pragma unroll
        for(int e=0;e<4;e++){ wp[16+e]=qss4[e]; wp[20+e]=kss4[e]; }
      }
    }
    __syncthreads();
    for(int c=tid; c<624; c+=512){
      float s = 0.f;
      if(c < 576){
        int d1o = c/24, d2o = c%24;
        int li = (d1o>>2)*6 + (d2o>>2);
        int sl = (d1o&3)*4 + (d2o&3);
        #pragma unroll
        for(int w8=0;w8<8;w8++) s += WRED[(w8*36+li)*25+sl];
        PAR[((size_t)chunk*96 + h*24 + d1o)*26 + d2o] = s;
      } else {
        int cc = c - 576;               // [0,48)
        int d = cc % 24, isk = cc / 24;
        int li = (d>>2)*7;              // diagonal lane
        int sl = 16 + isk*4 + (d&3);
        #pragma unroll
        for(int w8=0;w8<8;w8++) s += WRED[(w8*36+li)*25+sl];
        PAR[((size_t)chunk*96 + h*24 + d)*26 + 24 + isk] = s;
      }
    }
  }
}

// ---------------- CAEPAM: casm2 + caout2 (to LDS) + epam MFMA fused ----------------
__global__ __launch_bounds__(256) void k_caepam(
    const float* __restrict__ PAR, const void* __restrict__ t2,
    const float* __restrict__ VCA, const ushort_t* __restrict__ XH,
    const ushort_t* __restrict__ WE, const float* __restrict__ EB,
    const void* __restrict__ x, const void* __restrict__ gamma,
    float* __restrict__ SKIPF, ushort_t* __restrict__ SKIPH)
{
  __shared__ float A[2304];
  __shared__ float kinv_s[96];
  __shared__ ushort_t XR[64*200];   // 64 rows x 192 cols (stride 200 -> 2-way banks)
  int t = threadIdx.x;
  int n0 = blockIdx.x*64;
  float S[24]; float qi=0.f;
  int hh = (t<96)? t/24 : 0;
  if(t<96){
    float qss=0.f, kss=0.f;
    #pragma unroll
    for(int e=0;e<24;e++) S[e]=0.f;
    for(int c=0;c<16;c++){
      const float* pp = PAR + ((size_t)c*96+t)*26;
      #pragma unroll
      for(int e=0;e<24;e++) S[e] += pp[e];
      qss += pp[24]; kss += pp[25];
    }
    qi = 1.0f/fmaxf(sqrtf(qss),1e-12f);
    kinv_s[t] = 1.0f/fmaxf(sqrtf(kss),1e-12f);
  }
  __syncthreads();
  if(t<96){
    float tv = LD(t2,hh);
    float v[24]; float m = NEGINF;
    #pragma unroll
    for(int e=0;e<24;e++){
      v[e] = S[e]*qi*kinv_s[hh*24+e]*tv;
      m = fmaxf(m, v[e]);
    }
    float s=0.f;
    #pragma unroll
    for(int e=0;e<24;e++){ v[e]=__expf(v[e]-m); s+=v[e]; }
    float inv=1.0f/s;
    #pragma unroll
    for(int e=0;e<24;e++) A[t*24+e] = v[e]*inv;
  }
  __syncthreads();
  // copy attn cols 0..95 from XH global -> XR
  for(int f=t; f<3072; f+=256){
    int r = f/48, dp = f%48;
    unsigned pk = *reinterpret_cast<const unsigned*>(XH + (size_t)(n0+r)*192 + dp*2);
    *reinterpret_cast<unsigned*>(&XR[r*200 + dp*2]) = pk;
  }
  // x_ca -> XR cols 96..191
  {
    int h = t>>6, l = t&63;
    int n = n0 + l;
    float vr[24];
    const float* vp = VCA + ((size_t)h*NN+n)*24;
    #pragma unroll
    for(int e=0;e<24;e+=4){
      float4 v = *reinterpret_cast<const float4*>(vp+e);
      vr[e]=v.x; vr[e+1]=v.y; vr[e+2]=v.z; vr[e+3]=v.w;
    }
    #pragma unroll
    for(int d=0;d<24;d+=2){
      float a0=0.f, a1=0.f;
      const float* ar0 = A + (h*24+d)*24;
      const float* ar1 = ar0 + 24;
      #pragma unroll
      for(int e=0;e<24;e++){ a0 += ar0[e]*vr[e]; a1 += ar1[e]*vr[e]; }
      unsigned pk = (unsigned)f2b(a0) | ((unsigned)f2b(a1)<<16);
      *reinterpret_cast<unsigned*>(&XR[l*200 + 96 + h*24 + d]) = pk;
    }
  }
  __syncthreads();
  // epam MFMA: B from XR (LDS), A from WE; + x+1+gamma
  int w=t>>6, lane=t&63, lan=lane&15, grp=lane>>4;
  int n = n0 + w*16 + lan;
  const ushort_t* bp = &XR[(w*16+lan)*200];
  f32x4 acc[6];
  #pragma unroll
  for(int mt=0;mt<6;mt++) acc[mt] = (f32x4)(0.f);
  #pragma unroll
  for(int s=0;s<6;s++){
    s16x8 b = *reinterpret_cast<const s16x8*>(bp + s*32 + grp*8);
    #pragma unroll
    for(int mt=0;mt<6;mt++){
      s16x8 a = *reinterpret_cast<const s16x8*>(WE + (mt*16+lan)*192 + s*32 + grp*8);
      acc[mt] = __builtin_amdgcn_mfma_f32_16x16x32_bf16(a, b, acc[mt], 0,0,0);
    }
  }
  #pragma unroll
  for(int mt=0;mt<6;mt++){
    #pragma unroll
    for(int r=0;r<4;r++){
      int o = mt*16 + grp*4 + r;
      float e = acc[mt][r] + EB[o];
      float v = LD(x, o*NN+n) + 1.0f + LD(gamma,o)*e;
      SKIPF[(size_t)n*96+o] = v;
      SKIPH[(size_t)n*96+o] = f2b(v);
    }
  }
}

// ---------------- K10: conv3x3x3 (+ optional fused final GEMM for conv4) ------------
__global__ __launch_bounds__(256,2) void k_convm8(
    const ushort_t* __restrict__ IN, const ushort_t* __restrict__ WB2,
    const float* __restrict__ BNS, const float* __restrict__ resf,
    const float* __restrict__ ZB,
    ushort_t* __restrict__ outh, float* __restrict__ outf,
    const ushort_t* __restrict__ W8H8, const void* __restrict__ fb8,
    const float* __restrict__ skipf, float* __restrict__ finout)
{
  __shared__ ushort_t BUF[2][16640];
  int tid = threadIdx.x;
  int w = tid>>6, lane = tid&63;
  int lan = lane&15, grp = lane>>4;
  int bs = (blockIdx.x&7)*50 + (blockIdx.x>>3);
  int n0 = bs*64;

  auto STAGE = [&](int tap, ushort_t* buf){
    int dx=tap/9-1, dy=(tap%9)/3-1, dz=tap%3-1;
    int off = dx*640 + dy*16 + dz;
    const ushort_t* wsrc = WB2 + tap*9984;
    #pragma unroll
    for(int i=0;i<9;i++){
      int cb = i*256 + w*64;
      if(cb >= 2080) break;
      int c = cb + lane;
      const void* src;
      if(c < 1248){
        src = wsrc + c*8;
      } else {
        int c2 = c - 1248;
        int r = c2/13, p = c2%13;
        int nn = n0 + r;
        int X = nn/640, rr2 = nn%640, Y = rr2/16, Z = nn&15;
        bool ok = (p<12) && (unsigned)(X+dx)<40u && (unsigned)(Y+dy)<40u && (unsigned)(Z+dz)<16u;
        src = ok ? (const void*)(IN + (size_t)(nn+off)*96 + p*8) : (const void*)ZB;
      }
      if(c < 2080) gl_lds16(src, buf + cb*8);
    }
  };

  f32x4 acc[6];
  #pragma unroll
  for(int mt=0;mt<6;mt++) acc[mt] = (f32x4)(0.f);

  STAGE(0, BUF[0]);
  asm volatile("s_waitcnt vmcnt(0)" ::: "memory");
  __builtin_amdgcn_s_barrier();

  for(int tap=0; tap<27; ++tap){
    if(tap<26){
      STAGE(tap+1, BUF[(tap+1)&1]);
      asm volatile("s_waitcnt vmcnt(8)" ::: "memory");
    } else {
      asm volatile("s_waitcnt vmcnt(0)" ::: "memory");
    }
    __builtin_amdgcn_s_barrier();
    __builtin_amdgcn_sched_barrier(0);
    const ushort_t* Ab = BUF[tap&1];
    const ushort_t* Bb = Ab + 9984;
    s16x8 bfr[3];
    #pragma unroll
    for(int s=0;s<3;s++)
      bfr[s] = *reinterpret_cast<const s16x8*>(Bb + (w*16+lan)*104 + s*32 + grp*8);
    #pragma unroll
    for(int mt=0;mt<6;mt++){
      #pragma unroll
      for(int s=0;s<3;s++){
        s16x8 a = *reinterpret_cast<const s16x8*>(Ab + (mt*16+lan)*104 + s*32 + grp*8);
        acc[mt] = __builtin_amdgcn_mfma_f32_16x16x32_bf16(a, bfr[s], acc[mt], 0,0,0);
      }
    }
    __builtin_amdgcn_s_barrier();
  }

  float* TR = (float*)&BUF[0][0];          // 64 x 100 f32 (25.6 KB, fits BUF[0])
  ushort_t* FR = &BUF[1][0];               // 64 x 104 bf16 (fused final only)
  int nl = w*16 + lan;
  #pragma unroll
  for(int mt=0;mt<6;mt++){
    int ob = mt*16 + grp*4;
    float4 vv;
    vv.x = acc[mt][0]*BNS[ob+0] + BNS[96+ob+0];
    vv.y = acc[mt][1]*BNS[ob+1] + BNS[96+ob+1];
    vv.z = acc[mt][2]*BNS[ob+2] + BNS[96+ob+2];
    vv.w = acc[mt][3]*BNS[ob+3] + BNS[96+ob+3];
    *reinterpret_cast<float4*>(TR + nl*100 + ob) = vv;
  }
  __syncthreads();
  for(int f=tid; f<3072; f+=256){
    int r = f/48, cp = f%48;
    int n = n0 + r;
    float v0 = TR[r*100+cp*2], v1 = TR[r*100+cp*2+1];
    if(resf){ v0 += resf[(size_t)n*96+cp*2]; v1 += resf[(size_t)n*96+cp*2+1]; }
    v0 = (v0>=0.f)? v0 : 0.01f*v0;
    v1 = (v1>=0.f)? v1 : 0.01f*v1;
    unsigned pk = (unsigned)f2b(v0) | ((unsigned)f2b(v1)<<16);
    if(finout){
      *reinterpret_cast<unsigned*>(&FR[r*104 + cp*2]) = pk;
    } else {
      *reinterpret_cast<unsigned*>(outh + (size_t)n*96 + cp*2) = pk;
      if(outf){
        float2 fo; fo.x=v0; fo.y=v1;
        *reinterpret_cast<float2*>(outf + (size_t)n*96 + cp*2) = fo;
      }
    }
  }
  if(finout){
    __syncthreads();
    // final GEMM: out = SKIPF + W8 . h + b8   (h = FR rows, bf16)
    f32x4 acc2[6];
    #pragma unroll
    for(int mt=0;mt<6;mt++) acc2[mt] = (f32x4)(0.f);
    const ushort_t* bp = &FR[(w*16+lan)*104];
    #pragma unroll
    for(int s=0;s<3;s++){
      s16x8 bb = *reinterpret_cast<const s16x8*>(bp + s*32 + grp*8);
      #pragma unroll
      for(int mt=0;mt<6;mt++){
        s16x8 a = *reinterpret_cast<const s16x8*>(W8H8 + (mt*16+lan)*96 + s*32 + grp*8);
        acc2[mt] = __builtin_amdgcn_mfma_f32_16x16x32_bf16(a, bb, acc2[mt], 0,0,0);
      }
    }
    int n = n0 + w*16 + lan;
    #pragma unroll
    for(int mt=0;mt<6;mt++){
      #pragma unroll
      for(int r=0;r<4;r++){
        int o = mt*16 + grp*4 + r;
        finout[(size_t)o*NN+n] = skipf[(size_t)n*96+o] + acc2[mt][r] + LD(fb8,o);
      }
    }
  }
}

extern "C" void kernel_launch(void* const* d_in, const int* in_sizes, int n_in,
                              void* d_out, int out_size, void* d_ws, size_t ws_size,
                              hipStream_t stream){
  const void* x     = d_in[0];
  const int*  rpi   = (const int*)d_in[1];
  const void* rct   = d_in[2];
  const void* sls   = d_in[3];
  const void* nw    = d_in[4];
  const void* nb    = d_in[5];
  const void* gamma = d_in[6];
  const void* wqkvv = d_in[7];
  const void* temp  = d_in[8];
  const void* temp2 = d_in[9];
  const void* qe    = d_in[10];
  const void* rbl   = d_in[11];
  const void* ltok  = d_in[12];
  const void* lbias = d_in[13];
  const void* srw   = d_in[14];
  const void* srb   = d_in[15];
  const void* epaw  = d_in[16];
  const void* epab  = d_in[17];
  const void* wkv   = d_in[18];
  const void* c1w   = d_in[19];
  const void* c1b   = d_in[20];
  const void* c2w   = d_in[21];
  const void* c2b   = d_in[22];
  const void* o1w   = d_in[23];
  const void* o1b   = d_in[24];
  const void* o2w   = d_in[25];
  const void* o2b   = d_in[26];
  const void* w51a  = d_in[27];
  const void* bn51a = d_in[28];
  const void* w51b  = d_in[29];
  const void* bn51b = d_in[30];
  const void* w52a  = d_in[31];
  const void* bn52a = d_in[32];
  const void* w52b  = d_in[33];
  const void* bn52b = d_in[34];
  const void* w8    = d_in[35];
  const void* b8    = d_in[36];

  float* ws = (float*)d_ws;
  const size_t S = SSLOT;
  ushort_t* XNH = (ushort_t*)ws;
  float* SKIPF = ws;
  float* Q     = ws + 1*S;
  float* Kb    = ws + 2*S;
  float* T2F   = ws + 2*S;
  float* VCA   = ws + 3*S;
  ushort_t* KH = (ushort_t*)(ws + 4*S);
  ushort_t* VH = KH + SSLOT;
  float* QS    = ws + 6*S;
  ushort_t* XH = (ushort_t*)(ws + 7*S);
  int*   rpiT  = (int*)(ws + 8*S);
  float* XP2   = ws + 7*S;
  ushort_t* SKIPH = (ushort_t*)(ws + 4*S);
  ushort_t* T1H   = SKIPH + SSLOT;
  ushort_t* T2H   = (ushort_t*)(ws + 5*S);
  float* SM  = ws + 9*S;
  float* pooled = SM;            // 4800
  float* TAB    = SM + 19200;    // 16384
  ushort_t* WB2 = (ushort_t*)(SM + 40960);   // 4*269568 ushorts
  float* BNS    = SM + 40960 + 539136;       // 768
  ushort_t* WQH = (ushort_t*)(BNS + 768);    // 36864 ushorts
  ushort_t* WSH = WQH + 36864;               // 9216 ushorts
  ushort_t* W8H = WSH + 9216;                // 9216 ushorts
  ushort_t* WE  = W8H + 9216;                // 18432 ushorts
  float* EB     = BNS + 768 + 18432 + 4608 + 4608 + 9216; // 96
  float* PAR    = EB + 96;                   // 16*96*26 = 39936
  ushort_t* KPNH = (ushort_t*)(PAR + 39936); // 4800 ushorts
  ushort_t* VPH  = KPNH + 4800;              // 4800 ushorts
  ushort_t* LTOKT= VPH + 4800;               // 4096 ushorts
  ushort_t* LTH  = LTOKT + 4096;             // 2867200 ushorts
  float* ZB      = (float*)(LTH + 2867200);  // 8 floats

  k_mega  <<<9108, 256, 0, stream>>>(w51a, w51b, w52a, w52b, wqkvv, srw, w8,
                                     o1w, o1b, o2w, o2b,
                                     bn51a, bn51b, bn52a, bn52b, ltok,
                                     WB2, WQH, WSH, W8H, WE, EB, BNS, LTOKT, ZB,
                                     rpi, rpiT,
                                     x, nw, nb, XNH,
                                     rct, c1w, c1b, c2w, c2b, TAB);
  k_qkvsr <<<dim3(400,3), 256, 0, stream>>>(XNH, WQH, WSH, srb, Q, KH, VH, XP2);
  k_mid1  <<<1600, 256, 0, stream>>>(Q, temp, sls, qe, LTOKT, lbias, QS, LTH,
                                     XP2, pooled);
  k_mid2  <<<50,   256, 0, stream>>>(pooled, epaw, epab, wkv, KPNH, VPH);
  k_big   <<<464,  512, 0, stream>>>(QS, KH, VH, KPNH, VPH, TAB, rpiT,
                                     rbl, LTH, XH, Q, Kb, PAR);
  k_caepam<<<400,  256, 0, stream>>>(PAR, temp2, VCA, XH, WE, EB, x, gamma,
                                     SKIPF, SKIPH);
  // resblock 1
  k_convm8<<<400, 256, 0, stream>>>(SKIPH, WB2,      BNS,     nullptr, ZB, T1H, nullptr,
                                    nullptr, nullptr, nullptr, nullptr);
  k_convm8<<<400, 256, 0, stream>>>(T1H,   WB2+WP,   BNS+192, SKIPF,   ZB, T2H, T2F,
                                    nullptr, nullptr, nullptr, nullptr);
  // resblock 2
  k_convm8<<<400, 256, 0, stream>>>(T2H,   WB2+2*WP, BNS+384, nullptr, ZB, T1H, nullptr,
                                    nullptr, nullptr, nullptr, nullptr);
  // conv4 + fused final GEMM (skip + W8.h + b8) -> d_out
  k_convm8<<<400, 256, 0, stream>>>(T1H,   WB2+3*WP, BNS+576, T2F,     ZB, nullptr, nullptr,
                                    W8H, b8, SKIPF, (float*)d_out);
}

// Round 25
// 267.881 us; speedup vs baseline: 1.0385x; 1.0385x over previous
//
#include <hip/hip_runtime.h>
#include <hip/hip_bf16.h>

// Problem constants
#define NN 25600      // D*H*W = 16*40*40
#define CC 96
#define NHh 4
#define HDd 24
#define SSLOT 2457600 // NN*CC floats per workspace slot
#define WP 269568     // padded conv weight tensor: 27*96*104 ushorts

typedef unsigned short ushort_t;
typedef float f32x4 __attribute__((ext_vector_type(4)));
typedef short s16x8 __attribute__((ext_vector_type(8)));
typedef _Float16 f16;
typedef f16 h2v __attribute__((ext_vector_type(2)));

__device__ __forceinline__ float LD(const void* p, int i){
  return ((const float*)p)[i];
}
__device__ __forceinline__ float b2f(ushort_t u){ return __uint_as_float(((unsigned)u)<<16); }
__device__ __forceinline__ ushort_t f2b(float f){
  unsigned u = __float_as_uint(f);
  unsigned r = (u + 0x7fffu + ((u>>16)&1u))>>16;
  return (ushort_t)r;
}
__device__ __forceinline__ ushort_t f2h(float f){
  f16 hv = (f16)f;
  return *reinterpret_cast<ushort_t*>(&hv);
}
__device__ __forceinline__ float fdot2(h2v a, h2v b, float c){
#if __has_builtin(__builtin_amdgcn_fdot2)
  return __builtin_amdgcn_fdot2(a, b, c, false);
#else
  return c + (float)a[0]*(float)b[0] + (float)a[1]*(float)b[1];
#endif
}
__device__ __forceinline__ void gl_lds16(const void* g, const void* l){
  __builtin_amdgcn_global_load_lds(
      (const __attribute__((address_space(1))) unsigned*)g,
      (__attribute__((address_space(3))) unsigned*)l, 16, 0, 0);
}

#define NEGINF (-3.0e38f)

// ---------------- MEGA prologue: prepall | rpiT | ln | tab in one launch ------------
__global__ __launch_bounds__(256) void k_mega(
    const void* w0, const void* w1, const void* w2, const void* w3,
    const void* wq, const void* wsr, const void* w8,
    const void* o1w, const void* o1b, const void* o2w, const void* o2b,
    const void* b0, const void* b1, const void* b2bn, const void* b3,
    const void* ltok,
    ushort_t* __restrict__ WB2, ushort_t* __restrict__ WQH,
    ushort_t* __restrict__ WSH, ushort_t* __restrict__ W8H,
    ushort_t* __restrict__ WE, float* __restrict__ EB,
    float* __restrict__ BNS, ushort_t* __restrict__ LTOKT,
    float* __restrict__ ZB,
    const int* __restrict__ rpi, int* __restrict__ rpiT,
    const void* __restrict__ x, const void* __restrict__ nw,
    const void* __restrict__ nb, ushort_t* __restrict__ XNH,
    const void* __restrict__ rct, const void* __restrict__ w1t,
    const void* __restrict__ b1t, const void* __restrict__ w2t,
    const void* __restrict__ b2t, float* __restrict__ TAB)
{
  __shared__ __align__(16) char SMEM[15400];
  int b = blockIdx.x, tid = threadIdx.x;
  if(b < 4212){
    int e = b*256 + tid;
    {
      int t = e/WP, r = e%WP;
      int tap = r/9984, r2 = r%9984, o = r2/104, p = r2%104;
      const void* w = (t==0)? w0 : (t==1)? w1 : (t==2)? w2 : w3;
      WB2[e] = (p<96)? f2b(LD(w, (o*96+p)*27 + tap)) : (ushort_t)0;
    }
    if(e < 36864) WQH[e] = f2b(LD(wq,e));
    if(e < 9216){ WSH[e] = f2b(LD(wsr,e)); W8H[e] = f2b(LD(w8,e)); }
    if(e < 96*192){
      int o = e/192, c2 = e%192;
      float v = 0.f;
      if(o < 48 && c2 < 96)        v = LD(o1w, o*96 + c2);
      else if(o >= 48 && c2 >= 96) v = LD(o2w, (o-48)*96 + (c2-96));
      WE[e] = f2b(v);
      if(c2 == 0) EB[o] = (o<48)? LD(o1b,o) : LD(o2b,o-48);
    }
    if(e < 384){
      int t = e/96, o = e%96;
      const void* bn = (t==0)? b0 : (t==1)? b1 : (t==2)? b2bn : b3;
      float g=LD(bn,o), bb=LD(bn,96+o), mu=LD(bn,192+o), var=LD(bn,288+o);
      float s = g*rsqrtf(var+1e-5f);
      BNS[t*192+o] = s;
      BNS[t*192+96+o] = bb - mu*s;
    }
    if(e < 4096){
      int h = e/1024, r = e%1024, kk = r/32, d = r%32;
      float v = (d<24 && kk<27)? LD(ltok, (h*24+d)*27 + kk) : 0.f;
      LTOKT[e] = f2b(v);
    }
    if(e < 8) ZB[e] = 0.f;
  } else if(b < 4612){
    int* T = (int*)SMEM;                 // [50][65]
    int n0 = (b-4212)*64;
    for(int f=tid; f<3200; f+=256){
      int nl = f/50, p = f%50;
      T[p*65+nl] = rpi[n0*50 + f];
    }
    __syncthreads();
    for(int f=tid; f<3200; f+=256){
      int p = f>>6, nl = f&63;
      rpiT[(size_t)p*NN + n0 + nl] = T[p*65+nl];
    }
  } else if(b < 5012){
    float* reds  = (float*)SMEM;         // [4][64]
    float* redss = reds + 256;           // [4][64]
    ushort_t* OUT = (ushort_t*)(redss + 256); // [64][100]
    int bx = b - 4612;
    int nl = tid&63, cg = tid>>6;
    int n = bx*64 + nl;
    float v[24]; float s=0.f, ss=0.f;
    #pragma unroll
    for(int i=0;i<24;i++){
      float t = LD(x, (cg*24+i)*NN + n) + 1.0f;
      v[i]=t; s+=t; ss+=t*t;
    }
    reds[cg*64+nl]=s; redss[cg*64+nl]=ss;
    __syncthreads();
    float S  = reds[nl]+reds[64+nl]+reds[128+nl]+reds[192+nl];
    float SS = redss[nl]+redss[64+nl]+redss[128+nl]+redss[192+nl];
    float mu = S*(1.0f/CC);
    float inv = rsqrtf(SS*(1.0f/CC) - mu*mu + 1e-5f);
    #pragma unroll
    for(int i=0;i<24;i++){
      int c = cg*24+i;
      OUT[nl*100+c] = f2b((v[i]-mu)*inv*LD(nw,c) + LD(nb,c));
    }
    __syncthreads();
    for(int f=tid; f<3072; f+=256){
      int r = f/48, dp = f%48;
      unsigned pk = (unsigned)OUT[r*100+dp*2] | ((unsigned)OUT[r*100+dp*2+1]<<16);
      *reinterpret_cast<unsigned*>(XNH + (size_t)(bx*64+r)*96 + dp*2) = pk;
    }
  } else {
    float* red = (float*)SMEM;           // [16]
    int tt = b - 5012, j = tid;
    float r0=LD(rct,tt*3), r1=LD(rct,tt*3+1), r2=LD(rct,tt*3+2);
    float hA = r0*LD(w1t,j*3) + r1*LD(w1t,j*3+1) + r2*LD(w1t,j*3+2) + LD(b1t,j);
    hA = fmaxf(hA, 0.f);
    int j2 = j + 256;
    float hB = r0*LD(w1t,j2*3) + r1*LD(w1t,j2*3+1) + r2*LD(w1t,j2*3+2) + LD(b1t,j2);
    hB = fmaxf(hB, 0.f);
    int lane=j&63, wid=j>>6;
    for(int h=0;h<4;h++){
      float v = hA*LD(w2t, h*512+j) + hB*LD(w2t, h*512+j2);
      #pragma unroll
      for(int off=32;off;off>>=1) v += __shfl_down(v, off);
      if(lane==0) red[wid*4+h]=v;
    }
    __syncthreads();
    if(j<4){
      float s = red[j] + red[4+j] + red[8+j] + red[12+j];
      TAB[tt*4+j] = s + LD(b2t,j);
    }
  }
}

// ---------------- K2+K4 fused: qkvv (y=0,1) and sr+gelu (y=2) MFMA GEMMs -----------
__global__ __launch_bounds__(256,2) void k_qkvsr(
    const ushort_t* __restrict__ XNH, const ushort_t* __restrict__ WQH,
    const ushort_t* __restrict__ WSH, const void* __restrict__ srb,
    float* __restrict__ out, ushort_t* __restrict__ KH,
    ushort_t* __restrict__ VH, float* __restrict__ XP2){
  int tid=threadIdx.x, w=tid>>6, lane=tid&63, lan=lane&15, grp=lane>>4;
  int n = blockIdx.x*64 + w*16 + lan;
  const ushort_t* bp = XNH + n*96;
  if(blockIdx.y < 2){
    int ybase = blockIdx.y*192;
    f32x4 acc[12];
    #pragma unroll
    for(int mt=0;mt<12;mt++) acc[mt] = (f32x4)(0.f);
    #pragma unroll
    for(int s=0;s<3;s++){
      s16x8 b = *reinterpret_cast<const s16x8*>(bp + s*32 + grp*8);
      #pragma unroll
      for(int mt=0;mt<12;mt++){
        s16x8 a = *reinterpret_cast<const s16x8*>(WQH + (ybase+mt*16+lan)*96 + s*32 + grp*8);
        acc[mt] = __builtin_amdgcn_mfma_f32_16x16x32_bf16(a, b, acc[mt], 0,0,0);
      }
    }
    #pragma unroll
    for(int mt=0;mt<12;mt++){
      int o0 = ybase + mt*16 + grp*4;
      int sl = o0/96, rr = o0%96, h = rr/24, dd = rr%24;
      f32x4 v = acc[mt];
      if(sl == 3){
        ushort4 pk = { f2h(v[0]), f2h(v[1]), f2h(v[2]), f2h(v[3]) };
        *reinterpret_cast<ushort4*>(VH + ((size_t)h*NN+n)*24 + dd) = pk;
      } else {
        *reinterpret_cast<float4*>(out + sl*SSLOT + ((size_t)h*NN+n)*24 + dd) =
            (float4){v[0],v[1],v[2],v[3]};
        if(sl == 1){
          ushort4 pk = { f2h(v[0]), f2h(v[1]), f2h(v[2]), f2h(v[3]) };
          *reinterpret_cast<ushort4*>(KH + ((size_t)h*NN+n)*24 + dd) = pk;
        }
      }
    }
  } else {
    f32x4 acc[6];
    #pragma unroll
    for(int mt=0;mt<6;mt++) acc[mt] = (f32x4)(0.f);
    #pragma unroll
    for(int s=0;s<3;s++){
      s16x8 b = *reinterpret_cast<const s16x8*>(bp + s*32 + grp*8);
      #pragma unroll
      for(int mt=0;mt<6;mt++){
        s16x8 a = *reinterpret_cast<const s16x8*>(WSH + (mt*16+lan)*96 + s*32 + grp*8);
        acc[mt] = __builtin_amdgcn_mfma_f32_16x16x32_bf16(a, b, acc[mt], 0,0,0);
      }
    }
    #pragma unroll
    for(int mt=0;mt<6;mt++){
      #pragma unroll
      for(int r=0;r<4;r++){
        int o = mt*16 + grp*4 + r;
        float y = acc[mt][r] + LD(srb,o);
        y = 0.5f*y*(1.0f + erff(y*0.70710678118f));
        XP2[o*NN+n] = y;
      }
    }
  }
}

// ---------------- MID1: qsltm (b<400) | pool x4 (b>=400) ----------------
__global__ __launch_bounds__(256) void k_mid1(
    const float* __restrict__ Q, const void* __restrict__ temp,
    const void* __restrict__ sls, const void* __restrict__ qe,
    const ushort_t* __restrict__ LTOKT, const void* __restrict__ lbias,
    float* __restrict__ QS, ushort_t* __restrict__ LTH,
    const float* __restrict__ XP2, float* __restrict__ pooled)
{
  __shared__ ushort_t QL[4][64][32];   // 16 KB
  int b = blockIdx.x, tid = threadIdx.x;
  if(b < 400){
    int h = tid>>6, nl = tid&63;
    int n0 = b*64, n = n0 + nl;
    const float* qr = Q + ((size_t)h*NN+n)*24;
    float qv[24]; float ssum=0.f;
    #pragma unroll
    for(int d=0;d<24;d++){ qv[d]=qr[d]; ssum+=qv[d]*qv[d]; }
    float inv = 1.0f/fmaxf(sqrtf(ssum), 1e-12f);
    float t = LD(temp,h);
    float sp = log1pf(expf(t)) * LD(sls,0);
    float* qs = QS + ((size_t)h*NN+n)*24;
    #pragma unroll
    for(int d=0;d<24;d+=2){
      float q0 = qv[d]*inv, q1 = qv[d+1]*inv;
      unsigned pk = (unsigned)f2b(q0) | ((unsigned)f2b(q1)<<16);
      *reinterpret_cast<unsigned*>(&QL[h][nl][d]) = pk;
      qs[d]   = (q0 + LD(qe, h*24+d))*sp;
      qs[d+1] = (q1 + LD(qe, h*24+d+1))*sp;
    }
    *reinterpret_cast<unsigned*>(&QL[h][nl][24]) = 0;
    *reinterpret_cast<unsigned*>(&QL[h][nl][26]) = 0;
    *reinterpret_cast<unsigned*>(&QL[h][nl][28]) = 0;
    *reinterpret_cast<unsigned*>(&QL[h][nl][30]) = 0;
    __syncthreads();
    int lane=tid&63, lan=lane&15, grp=lane>>4;
    f32x4 acc[4][2];
    #pragma unroll
    for(int j=0;j<4;j++)
      #pragma unroll
      for(int tt=0;tt<2;tt++) acc[j][tt] = (f32x4)(0.f);
    #pragma unroll
    for(int j=0;j<4;j++){
      s16x8 bb = *reinterpret_cast<const s16x8*>(&QL[h][j*16+lan][grp*8]);
      #pragma unroll
      for(int tt=0;tt<2;tt++){
        s16x8 a = *reinterpret_cast<const s16x8*>(LTOKT + h*1024 + (tt*16+lan)*32 + grp*8);
        acc[j][tt] = __builtin_amdgcn_mfma_f32_16x16x32_bf16(a, bb, acc[j][tt], 0,0,0);
      }
    }
    #pragma unroll
    for(int j=0;j<4;j++){
      int nn = n0 + j*16 + lan;
      #pragma unroll
      for(int tt=0;tt<2;tt++){
        int k0 = tt*16 + grp*4;
        if(k0 < 28){
          ushort4 pk;
          ushort_t* pp = reinterpret_cast<ushort_t*>(&pk);
          #pragma unroll
          for(int r=0;r<4;r++){
            int k = k0+r;
            float v = acc[j][tt][r] + ((k<27)? LD(lbias, h*27+k) : 0.f);
            pp[r] = f2h(v);
          }
          *reinterpret_cast<ushort4*>(LTH + ((size_t)h*NN+nn)*28 + k0) = pk;
        }
      }
    }
  } else {
    int w = tid>>6, lane = tid&63;
    int pb = (b-400)*4 + w;              // [0,4800)
    int c = pb % CC, p = pb / CC;
    int ph = p/10, pw = (p%10)/2, pd = p%2;
    float s = 0.f;
    for(int t=lane; t<512; t+=64){
      int i=t>>6, j=(t>>3)&7, k=t&7;
      int m = (ph*8+i)*640 + (pw*8+j)*16 + (pd*8+k);
      s += XP2[c*NN+m];
    }
    #pragma unroll
    for(int off=32;off;off>>=1) s += __shfl_down(s, off);
    if(lane==0) pooled[p*CC+c] = s*(1.0f/512.0f);
  }
}

// ---------------- MID2: LN(pooled) + kv + inlined kpn -> KPNH/VPH f16 ---------------
__global__ void k_mid2(const float* __restrict__ pooled, const void* __restrict__ ew,
                       const void* __restrict__ eb, const void* __restrict__ wkv,
                       ushort_t* __restrict__ KPNH, ushort_t* __restrict__ VPH){
  __shared__ float row[96], lnr[96], st[2], kk[96];
  int p = blockIdx.x, t = threadIdx.x;
  if(t<96) row[t] = pooled[p*96+t];
  __syncthreads();
  if(t==0){
    float s=0.f, ss=0.f;
    for(int c=0;c<96;c++){ float v=row[c]; s+=v; ss+=v*v; }
    float mu=s*(1.0f/96.0f);
    float var=ss*(1.0f/96.0f)-mu*mu;
    st[0]=mu; st[1]=rsqrtf(var+1e-5f);
  }
  __syncthreads();
  if(t<96) lnr[t] = (row[t]-st[0])*st[1]*LD(ew,t) + LD(eb,t);
  __syncthreads();
  if(t<192){
    float a=0.f;
    for(int c=0;c<96;c++) a += LD(wkv, t*96+c)*lnr[c];
    int g=t/24, d=t%24;
    if(g<4) kk[t]=a;
    else    VPH[((g-4)*50+p)*24+d] = f2h(a);
  }
  __syncthreads();
  if(t<96){
    int g=t/24, d=t%24;
    float ss=0.f;
    #pragma unroll
    for(int e=0;e<24;e++){ float v=kk[g*24+e]; ss+=v*v; }
    float inv = 1.0f/fmaxf(sqrtf(ss),1e-12f);
    KPNH[((g*50+p)*24)+d] = f2h(kk[t]*inv);
  }
}

// ---------------- BIG: cascore3 FIRST (b<64) | attn6 (b in [64,464)) ----------------
__global__ __launch_bounds__(512) void k_big(
    const float* __restrict__ QS, const ushort_t* __restrict__ KH,
    const ushort_t* __restrict__ VH,
    const ushort_t* __restrict__ KPNH, const ushort_t* __restrict__ VPH,
    const float* __restrict__ TAB, const int* __restrict__ rpiT,
    const void* __restrict__ rbl, const ushort_t* __restrict__ LTH,
    ushort_t* __restrict__ XH,
    const float* __restrict__ Q, const float* __restrict__ K,
    float* __restrict__ PAR)
{
  __shared__ ushort_t KVH[2][600*26];   // 62.4 KB (aliased by cascore3's reduce)
  int bb = blockIdx.x, tid = threadIdx.x;
  if(bb >= 64){
    int bb2 = bb - 64;
    int tile = bb2 % 100, h = bb2 / 100;
    int g = tile/25, sp = tile%25, hg = sp/5, wg = sp%5;
    int role = tid>>8, q = tid & 255;
    int wq = q>>6, l = q&63;
    int hy = l>>3, wx = l&7;
    int d0 = g*4 + wq;
    int h0 = hg*8+hy, w0 = wg*8+wx;
    int n = d0*1600 + h0*40 + w0;

    const ushort_t* KHh = KH + (size_t)h*NN*24;
    const ushort_t* VHh = VH + (size_t)h*NN*24;
    for(int f=tid; f<3600; f+=512){
      int t = f/1800, rem = f%1800, row = rem/3, qq = rem%3;
      int dr = row/100, yr = (row%100)/10, xr = row%10;
      int zc = min(max(g*4+dr-1,0),15), yc = min(max(hg*8+yr-1,0),39), xc = min(max(wg*8+xr-1,0),39);
      const ushort_t* src = (t? VHh : KHh) + (size_t)(zc*1600+yc*40+xc)*24 + qq*8;
      const unsigned* s32 = reinterpret_cast<const unsigned*>(src);
      unsigned a0=s32[0], a1=s32[1], a2=s32[2], a3=s32[3];
      unsigned* d32 = reinterpret_cast<unsigned*>(&KVH[t][row*26 + qq*8]);
      d32[0]=a0; d32[1]=a1; d32[2]=a2; d32[3]=a3;
    }

    h2v qp[12];
    {
      const float* qsp = QS + ((size_t)h*NN+n)*24;
      #pragma unroll
      for(int d=0; d<24; d+=4){
        float4 a = *reinterpret_cast<const float4*>(qsp+d);
        qp[d/2]   = (h2v){ (f16)a.x, (f16)a.y };
        qp[d/2+1] = (h2v){ (f16)a.z, (f16)a.w };
      }
    }
    __syncthreads();

    float m_r, s_r;
    h2v accA[12], accT[12];
    #pragma unroll
    for(int j=0;j<12;j++){ accA[j]=(h2v){(f16)0.f,(f16)0.f}; accT[j]=(h2v){(f16)0.f,(f16)0.f}; }

    const h2v* kph = reinterpret_cast<const h2v*>(KPNH) + (size_t)h*50*12;
    const h2v* vph = reinterpret_cast<const h2v*>(VPH)  + (size_t)h*50*12;

    if(role==0){
      float av[39]; unsigned okm=0;
      #pragma unroll
      for(int k=0;k<27;k++){
        int kz=k/9, ky=(k%9)/3, kx=k%3;
        bool ok = (unsigned)(d0+kz-1)<16u && (unsigned)(h0+ky-1)<40u && (unsigned)(w0+kx-1)<40u;
        float sc = NEGINF;
        if(ok){
          okm |= 1u<<k;
          const h2v* kr = reinterpret_cast<const h2v*>(
              &KVH[0][((wq+kz)*100 + (hy+ky)*10 + (wx+kx))*26]);
          sc = LD(rbl, h*27+k);
          #pragma unroll
          for(int j=0;j<12;j++) sc = fdot2(kr[j], qp[j], sc);
        }
        av[k]=sc;
      }
      #pragma unroll
      for(int p=0;p<12;p++){
        float sc = TAB[rpiT[(size_t)p*NN+n]*4 + h];
        const h2v* kr = kph + p*12;
        #pragma unroll
        for(int j=0;j<12;j++) sc = fdot2(kr[j], qp[j], sc);
        av[27+p]=sc;
      }
      float m = av[0];
      #pragma unroll
      for(int k=1;k<39;k++) m = fmaxf(m, av[k]);
      const f16* ltp = reinterpret_cast<const f16*>(LTH) + ((size_t)h*NN+n)*28;
      float s = 0.f;
      #pragma unroll
      for(int k=0;k<27;k++){
        if(okm>>k & 1u){
          int kz=k/9, ky=(k%9)/3, kx=k%3;
          float e = __expf(av[k]-m);
          s += e;
          float ltv = (float)ltp[k];
          h2v we = { (f16)e, (f16)e };
          h2v wt = { (f16)ltv, (f16)ltv };
          const h2v* vr = reinterpret_cast<const h2v*>(
              &KVH[1][((wq+kz)*100 + (hy+ky)*10 + (wx+kx))*26]);
          #pragma unroll
          for(int j=0;j<12;j++){
            accA[j] = vr[j]*we + accA[j];
            accT[j] = vr[j]*wt + accT[j];
          }
        }
      }
      #pragma unroll
      for(int p=0;p<12;p++){
        float e = __expf(av[27+p]-m);
        s += e;
        h2v we = { (f16)e, (f16)e };
        const h2v* vr = vph + p*12;
        #pragma unroll
        for(int j=0;j<12;j++) accA[j] = vr[j]*we + accA[j];
      }
      m_r = m; s_r = s;
    } else {
      float av[38];
      #pragma unroll
      for(int p=0;p<38;p++){
        int pp = p+12;
        float sc = TAB[rpiT[(size_t)pp*NN+n]*4 + h];
        const h2v* kr = kph + pp*12;
        #pragma unroll
        for(int j=0;j<12;j++) sc = fdot2(kr[j], qp[j], sc);
        av[p]=sc;
      }
      float m = av[0];
      #pragma unroll
      for(int p=1;p<38;p++) m = fmaxf(m, av[p]);
      float s = 0.f;
      #pragma unroll
      for(int p=0;p<38;p++){
        float e = __expf(av[p]-m);
        s += e;
        h2v we = { (f16)e, (f16)e };
        const h2v* vr = vph + (p+12)*12;
        #pragma unroll
        for(int j=0;j<12;j++) accA[j] = vr[j]*we + accA[j];
      }
      m_r = m; s_r = s;
    }
    __syncthreads();

    float* PP = (float*)&KVH[0][0];
    if(role==1){
      PP[q*15+0] = m_r;
      PP[q*15+1] = s_r;
      #pragma unroll
      for(int j=0;j<12;j++){
        h2v a = accA[j];
        PP[q*15+2+j] = __uint_as_float(*reinterpret_cast<unsigned*>(&a));
      }
    }
    __syncthreads();

    float* TRF = (float*)&KVH[0][0] + 4096;
    if(role==0){
      float mp = PP[q*15+0], sp2 = PP[q*15+1];
      float m = fmaxf(m_r, mp);
      float a = __expf(m_r - m), b = __expf(mp - m);
      float inv = 1.0f/(a*s_r + b*sp2);
      #pragma unroll
      for(int j=0;j<12;j++){
        unsigned pb = __float_as_uint(PP[q*15+2+j]);
        h2v ap = *reinterpret_cast<h2v*>(&pb);
        float v0 = (a*(float)accA[j][0] + b*(float)ap[0])*inv + (float)accT[j][0];
        float v1 = (a*(float)accA[j][1] + b*(float)ap[1])*inv + (float)accT[j][1];
        TRF[q*25 + 2*j]   = v0;
        TRF[q*25 + 2*j+1] = v1;
      }
    }
    __syncthreads();

    for(int f=tid; f<3072; f+=512){
      int q2 = f/12, dp = f%12;
      int w2 = q2>>6, l2 = q2&63;
      int n2 = (g*4+w2)*1600 + (hg*8+(l2>>3))*40 + (wg*8+(l2&7));
      float v0 = TRF[q2*25+dp*2], v1 = TRF[q2*25+dp*2+1];
      unsigned pk = (unsigned)f2b(v0) | ((unsigned)f2b(v1)<<16);
      *reinterpret_cast<unsigned*>(XH + (size_t)n2*192 + h*24 + dp*2) = pk;
    }
  } else {
    // cascore3: register-tiled QtK. 64 blocks: (h, chunk16). Q,K read exactly once.
    float* WRED = (float*)&KVH[0][0];    // [8 waves][36 lanes][25] = 28.8 KB
    int b2 = bb;                         // [0,64)
    int h = b2 >> 4, chunk = b2 & 15;
    int wv = tid >> 6, lane = tid & 63;
    int n0 = chunk*1600 + wv*200;
    const float* Qh = Q + (size_t)h*NN*24;
    const float* Kh = K + (size_t)h*NN*24;
    int r = lane/6, cgl = lane%6;
    bool act = lane < 36;
    int d1 = r*4, d2 = cgl*4;
    float accm[4][4];
    #pragma unroll
    for(int i=0;i<4;i++)
      #pragma unroll
      for(int j=0;j<4;j++) accm[i][j]=0.f;
    float qss4[4] = {0.f,0.f,0.f,0.f}, kss4[4] = {0.f,0.f,0.f,0.f};
    if(act){
      #pragma unroll 4
      for(int i=0;i<200;i++){
        int n = n0 + i;
        float4 q4 = *reinterpret_cast<const float4*>(Qh + (size_t)n*24 + d1);
        float4 k4 = *reinterpret_cast<const float4*>(Kh + (size_t)n*24 + d2);
        float qa[4] = {q4.x,q4.y,q4.z,q4.w};
        float ka[4] = {k4.x,k4.y,k4.z,k4.w};
        #pragma unroll
        for(int i2=0;i2<4;i2++)
          #pragma unroll
          for(int j=0;j<4;j++) accm[i2][j] += qa[i2]*ka[j];
        #pragma unroll
        for(int e=0;e<4;e++){ qss4[e]+=qa[e]*qa[e]; kss4[e]+=ka[e]*ka[e]; }
      }
      float* wp = WRED + (wv*36 + lane)*25;
      #pragma unroll
      for(int i=0;i<4;i++)
        #pragma unroll
        for(int j=0;j<4;j++) wp[i*4+j] = accm[i][j];
      if(r == cgl){
        #pragma unroll
        for(int e=0;e<4;e++){ wp[16+e]=qss4[e]; wp[20+e]=kss4[e]; }
      }
    }
    __syncthreads();
    for(int c=tid; c<624; c+=512){
      float s = 0.f;
      if(c < 576){
        int d1o = c/24, d2o = c%24;
        int li = (d1o>>2)*6 + (d2o>>2);
        int sl = (d1o&3)*4 + (d2o&3);
        #pragma unroll
        for(int w8=0;w8<8;w8++) s += WRED[(w8*36+li)*25+sl];
        PAR[((size_t)chunk*96 + h*24 + d1o)*26 + d2o] = s;
      } else {
        int cc = c - 576;               // [0,48)
        int d = cc % 24, isk = cc / 24;
        int li = (d>>2)*7;              // diagonal lane
        int sl = 16 + isk*4 + (d&3);
        #pragma unroll
        for(int w8=0;w8<8;w8++) s += WRED[(w8*36+li)*25+sl];
        PAR[((size_t)chunk*96 + h*24 + d)*26 + 24 + isk] = s;
      }
    }
  }
}

// ---------------- CAEP: casm2 recomputed in-block (16 chunks) + caout2 --------------
__global__ __launch_bounds__(256) void k_caep(
    const float* __restrict__ PAR, const void* __restrict__ t2,
    const float* __restrict__ VCA, ushort_t* __restrict__ XH){
  __shared__ float A[2304];
  __shared__ float kinv_s[96];
  int t = threadIdx.x;
  float S[24]; float qi=0.f;
  int hh = (t<96)? t/24 : 0;
  if(t<96){
    float qss=0.f, kss=0.f;
    #pragma unroll
    for(int e=0;e<24;e++) S[e]=0.f;
    for(int c=0;c<16;c++){
      const float* pp = PAR + ((size_t)c*96+t)*26;
      #pragma unroll
      for(int e=0;e<24;e++) S[e] += pp[e];
      qss += pp[24]; kss += pp[25];
    }
    qi = 1.0f/fmaxf(sqrtf(qss),1e-12f);
    kinv_s[t] = 1.0f/fmaxf(sqrtf(kss),1e-12f);
  }
  __syncthreads();
  if(t<96){
    float tv = LD(t2,hh);
    float v[24]; float m = NEGINF;
    #pragma unroll
    for(int e=0;e<24;e++){
      v[e] = S[e]*qi*kinv_s[hh*24+e]*tv;
      m = fmaxf(m, v[e]);
    }
    float s=0.f;
    #pragma unroll
    for(int e=0;e<24;e++){ v[e]=__expf(v[e]-m); s+=v[e]; }
    float inv=1.0f/s;
    #pragma unroll
    for(int e=0;e<24;e++) A[t*24+e] = v[e]*inv;
  }
  __syncthreads();
  int h = t>>6, l = t&63;
  int n = blockIdx.x*64 + l;
  float vr[24];
  const float* vp = VCA + ((size_t)h*NN+n)*24;
  #pragma unroll
  for(int e=0;e<24;e+=4){
    float4 v = *reinterpret_cast<const float4*>(vp+e);
    vr[e]=v.x; vr[e+1]=v.y; vr[e+2]=v.z; vr[e+3]=v.w;
  }
  float o[24];
  #pragma unroll
  for(int d=0;d<24;d++){
    float a=0.f;
    const float* ar = A + (h*24+d)*24;
    #pragma unroll
    for(int e=0;e<24;e++) a += ar[e]*vr[e];
    o[d]=a;
  }
  #pragma unroll
  for(int d=0;d<24;d+=2){
    unsigned pk = (unsigned)f2b(o[d]) | ((unsigned)f2b(o[d+1])<<16);
    *reinterpret_cast<unsigned*>(XH + (size_t)n*192 + 96 + h*24 + d) = pk;
  }
}

// ---------------- K9: epa MFMA (K=192 block-diagonal) + x+1+gamma fused ----------
__global__ __launch_bounds__(256,2) void k_epam(
    const ushort_t* __restrict__ XH, const ushort_t* __restrict__ WE,
    const float* __restrict__ EB, const void* __restrict__ x,
    const void* __restrict__ gamma,
    float* __restrict__ SKIPF, ushort_t* __restrict__ SKIPH){
  int tid=threadIdx.x, w=tid>>6, lane=tid&63, lan=lane&15, grp=lane>>4;
  int n = blockIdx.x*64 + w*16 + lan;
  const ushort_t* bp = XH + (size_t)n*192;
  f32x4 acc[6];
  #pragma unroll
  for(int mt=0;mt<6;mt++) acc[mt] = (f32x4)(0.f);
  #pragma unroll
  for(int s=0;s<6;s++){
    s16x8 b = *reinterpret_cast<const s16x8*>(bp + s*32 + grp*8);
    #pragma unroll
    for(int mt=0;mt<6;mt++){
      s16x8 a = *reinterpret_cast<const s16x8*>(WE + (mt*16+lan)*192 + s*32 + grp*8);
      acc[mt] = __builtin_amdgcn_mfma_f32_16x16x32_bf16(a, b, acc[mt], 0,0,0);
    }
  }
  #pragma unroll
  for(int mt=0;mt<6;mt++){
    #pragma unroll
    for(int r=0;r<4;r++){
      int o = mt*16 + grp*4 + r;
      float e = acc[mt][r] + EB[o];
      float v = LD(x, o*NN+n) + 1.0f + LD(gamma,o)*e;
      SKIPF[(size_t)n*96+o] = v;
      SKIPH[(size_t)n*96+o] = f2b(v);
    }
  }
}

// ---------------- K10: conv3x3x3, async gl_lds + 32nx48out wave tiling --------------
// Wave w = (ng=w&1 : 32-row n-group, og=w>>1 : 48-col out-group).
// Per tap per wave: 6 B-reads + 9 A-reads feed 18 MFMAs (was 3+18 for 18).
__global__ __launch_bounds__(256,2) void k_convm9(
    const ushort_t* __restrict__ IN, const ushort_t* __restrict__ WB2,
    const float* __restrict__ BNS, const float* __restrict__ resf,
    const float* __restrict__ ZB,
    ushort_t* __restrict__ outh, float* __restrict__ outf)
{
  __shared__ ushort_t BUF[2][16640];
  int tid = threadIdx.x;
  int w = tid>>6, lane = tid&63;
  int lan = lane&15, grp = lane>>4;
  int ng = w&1, og = w>>1;
  int bs = (blockIdx.x&7)*50 + (blockIdx.x>>3);
  int n0 = bs*64;

  auto STAGE = [&](int tap, ushort_t* buf){
    int dx=tap/9-1, dy=(tap%9)/3-1, dz=tap%3-1;
    int off = dx*640 + dy*16 + dz;
    const ushort_t* wsrc = WB2 + tap*9984;
    #pragma unroll
    for(int i=0;i<9;i++){
      int cb = i*256 + w*64;
      if(cb >= 2080) break;
      int c = cb + lane;
      const void* src;
      if(c < 1248){
        src = wsrc + c*8;
      } else {
        int c2 = c - 1248;
        int r = c2/13, p = c2%13;
        int nn = n0 + r;
        int X = nn/640, rr2 = nn%640, Y = rr2/16, Z = nn&15;
        bool ok = (p<12) && (unsigned)(X+dx)<40u && (unsigned)(Y+dy)<40u && (unsigned)(Z+dz)<16u;
        src = ok ? (const void*)(IN + (size_t)(nn+off)*96 + p*8) : (const void*)ZB;
      }
      if(c < 2080) gl_lds16(src, buf + cb*8);
    }
  };

  f32x4 acc[2][3];
  #pragma unroll
  for(int nt=0;nt<2;nt++)
    #pragma unroll
    for(int mt=0;mt<3;mt++) acc[nt][mt] = (f32x4)(0.f);

  STAGE(0, BUF[0]);
  asm volatile("s_waitcnt vmcnt(0)" ::: "memory");
  __builtin_amdgcn_s_barrier();

  for(int tap=0; tap<27; ++tap){
    if(tap<26){
      STAGE(tap+1, BUF[(tap+1)&1]);
      asm volatile("s_waitcnt vmcnt(8)" ::: "memory");
    } else {
      asm volatile("s_waitcnt vmcnt(0)" ::: "memory");
    }
    __builtin_amdgcn_s_barrier();
    __builtin_amdgcn_sched_barrier(0);
    const ushort_t* Ab = BUF[tap&1];
    const ushort_t* Bb = Ab + 9984;
    #pragma unroll
    for(int s=0;s<3;s++){
      s16x8 b0 = *reinterpret_cast<const s16x8*>(Bb + (ng*32 +      lan)*104 + s*32 + grp*8);
      s16x8 b1 = *reinterpret_cast<const s16x8*>(Bb + (ng*32 + 16 + lan)*104 + s*32 + grp*8);
      #pragma unroll
      for(int mt=0;mt<3;mt++){
        s16x8 a = *reinterpret_cast<const s16x8*>(Ab + (og*48 + mt*16 + lan)*104 + s*32 + grp*8);
        acc[0][mt] = __builtin_amdgcn_mfma_f32_16x16x32_bf16(a, b0, acc[0][mt], 0,0,0);
        acc[1][mt] = __builtin_amdgcn_mfma_f32_16x16x32_bf16(a, b1, acc[1][mt], 0,0,0);
      }
    }
    __builtin_amdgcn_s_barrier();
  }

  float* TR = (float*)&BUF[0][0];
  #pragma unroll
  for(int nt=0;nt<2;nt++){
    int nl = ng*32 + nt*16 + lan;
    #pragma unroll
    for(int mt=0;mt<3;mt++){
      int ob = og*48 + mt*16 + grp*4;
      float4 vv;
      vv.x = acc[nt][mt][0]*BNS[ob+0] + BNS[96+ob+0];
      vv.y = acc[nt][mt][1]*BNS[ob+1] + BNS[96+ob+1];
      vv.z = acc[nt][mt][2]*BNS[ob+2] + BNS[96+ob+2];
      vv.w = acc[nt][mt][3]*BNS[ob+3] + BNS[96+ob+3];
      *reinterpret_cast<float4*>(TR + nl*100 + ob) = vv;
    }
  }
  __syncthreads();
  for(int f=tid; f<3072; f+=256){
    int r = f/48, cp = f%48;
    int n = n0 + r;
    float v0 = TR[r*100+cp*2], v1 = TR[r*100+cp*2+1];
    if(resf){ v0 += resf[(size_t)n*96+cp*2]; v1 += resf[(size_t)n*96+cp*2+1]; }
    v0 = (v0>=0.f)? v0 : 0.01f*v0;
    v1 = (v1>=0.f)? v1 : 0.01f*v1;
    unsigned pk = (unsigned)f2b(v0) | ((unsigned)f2b(v1)<<16);
    *reinterpret_cast<unsigned*>(outh + (size_t)n*96 + cp*2) = pk;
    if(outf){
      float2 fo; fo.x=v0; fo.y=v1;
      *reinterpret_cast<float2*>(outf + (size_t)n*96 + cp*2) = fo;
    }
  }
}

// ---------------- K11: MFMA final ----------------
__global__ __launch_bounds__(256,2) void k_finm(
    const float* __restrict__ SKIPF, const ushort_t* __restrict__ T3H,
    const ushort_t* __restrict__ W8H, const void* __restrict__ b,
    float* __restrict__ out){
  int tid=threadIdx.x, w=tid>>6, lane=tid&63, lan=lane&15, grp=lane>>4;
  int n = blockIdx.x*64 + w*16 + lan;
  const ushort_t* bp = T3H + n*96;
  f32x4 acc[6];
  #pragma unroll
  for(int mt=0;mt<6;mt++) acc[mt] = (f32x4)(0.f);
  #pragma unroll
  for(int s=0;s<3;s++){
    s16x8 bb = *reinterpret_cast<const s16x8*>(bp + s*32 + grp*8);
    #pragma unroll
    for(int mt=0;mt<6;mt++){
      s16x8 a = *reinterpret_cast<const s16x8*>(W8H + (mt*16+lan)*96 + s*32 + grp*8);
      acc[mt] = __builtin_amdgcn_mfma_f32_16x16x32_bf16(a, bb, acc[mt], 0,0,0);
    }
  }
  #pragma unroll
  for(int mt=0;mt<6;mt++){
    #pragma unroll
    for(int r=0;r<4;r++){
      int o = mt*16 + grp*4 + r;
      out[o*NN+n] = SKIPF[(size_t)n*96+o] + acc[mt][r] + LD(b,o);
    }
  }
}

extern "C" void kernel_launch(void* const* d_in, const int* in_sizes, int n_in,
                              void* d_out, int out_size, void* d_ws, size_t ws_size,
                              hipStream_t stream){
  const void* x     = d_in[0];
  const int*  rpi   = (const int*)d_in[1];
  const void* rct   = d_in[2];
  const void* sls   = d_in[3];
  const void* nw    = d_in[4];
  const void* nb    = d_in[5];
  const void* gamma = d_in[6];
  const void* wqkvv = d_in[7];
  const void* temp  = d_in[8];
  const void* temp2 = d_in[9];
  const void* qe    = d_in[10];
  const void* rbl   = d_in[11];
  const void* ltok  = d_in[12];
  const void* lbias = d_in[13];
  const void* srw   = d_in[14];
  const void* srb   = d_in[15];
  const void* epaw  = d_in[16];
  const void* epab  = d_in[17];
  const void* wkv   = d_in[18];
  const void* c1w   = d_in[19];
  const void* c1b   = d_in[20];
  const void* c2w   = d_in[21];
  const void* c2b   = d_in[22];
  const void* o1w   = d_in[23];
  const void* o1b   = d_in[24];
  const void* o2w   = d_in[25];
  const void* o2b   = d_in[26];
  const void* w51a  = d_in[27];
  const void* bn51a = d_in[28];
  const void* w51b  = d_in[29];
  const void* bn51b = d_in[30];
  const void* w52a  = d_in[31];
  const void* bn52a = d_in[32];
  const void* w52b  = d_in[33];
  const void* bn52b = d_in[34];
  const void* w8    = d_in[35];
  const void* b8    = d_in[36];

  float* ws = (float*)d_ws;
  const size_t S = SSLOT;
  ushort_t* XNH = (ushort_t*)ws;
  float* SKIPF = ws;
  float* Q     = ws + 1*S;
  float* Kb    = ws + 2*S;
  float* T2F   = ws + 2*S;
  float* VCA   = ws + 3*S;
  ushort_t* KH = (ushort_t*)(ws + 4*S);
  ushort_t* VH = KH + SSLOT;
  float* QS    = ws + 6*S;
  ushort_t* XH = (ushort_t*)(ws + 7*S);
  int*   rpiT  = (int*)(ws + 8*S);
  float* XP2   = ws + 7*S;
  ushort_t* SKIPH = (ushort_t*)(ws + 4*S);
  ushort_t* T1H   = SKIPH + SSLOT;
  ushort_t* T2H   = (ushort_t*)(ws + 5*S);
  ushort_t* T3H   = T2H + SSLOT;
  float* SM  = ws + 9*S;
  float* pooled = SM;            // 4800
  float* TAB    = SM + 19200;    // 16384
  ushort_t* WB2 = (ushort_t*)(SM + 40960);   // 4*269568 ushorts
  float* BNS    = SM + 40960 + 539136;       // 768
  ushort_t* WQH = (ushort_t*)(BNS + 768);    // 36864 ushorts
  ushort_t* WSH = WQH + 36864;               // 9216 ushorts
  ushort_t* W8H = WSH + 9216;                // 9216 ushorts
  ushort_t* WE  = W8H + 9216;                // 18432 ushorts
  float* EB     = BNS + 768 + 18432 + 4608 + 4608 + 9216; // 96
  float* PAR    = EB + 96;                   // 16*96*26 = 39936
  ushort_t* KPNH = (ushort_t*)(PAR + 39936); // 4800 ushorts
  ushort_t* VPH  = KPNH + 4800;              // 4800 ushorts
  ushort_t* LTOKT= VPH + 4800;               // 4096 ushorts
  ushort_t* LTH  = LTOKT + 4096;             // 2867200 ushorts
  float* ZB      = (float*)(LTH + 2867200);  // 8 floats

  k_mega  <<<9108, 256, 0, stream>>>(w51a, w51b, w52a, w52b, wqkvv, srw, w8,
                                     o1w, o1b, o2w, o2b,
                                     bn51a, bn51b, bn52a, bn52b, ltok,
                                     WB2, WQH, WSH, W8H, WE, EB, BNS, LTOKT, ZB,
                                     rpi, rpiT,
                                     x, nw, nb, XNH,
                                     rct, c1w, c1b, c2w, c2b, TAB);
  k_qkvsr <<<dim3(400,3), 256, 0, stream>>>(XNH, WQH, WSH, srb, Q, KH, VH, XP2);
  k_mid1  <<<1600, 256, 0, stream>>>(Q, temp, sls, qe, LTOKT, lbias, QS, LTH,
                                     XP2, pooled);
  k_mid2  <<<50,   256, 0, stream>>>(pooled, epaw, epab, wkv, KPNH, VPH);
  k_big   <<<464,  512, 0, stream>>>(QS, KH, VH, KPNH, VPH, TAB, rpiT,
                                     rbl, LTH, XH, Q, Kb, PAR);
  k_caep  <<<400,  256, 0, stream>>>(PAR, temp2, VCA, XH);
  k_epam  <<<400,  256, 0, stream>>>(XH, WE, EB, x, gamma, SKIPF, SKIPH);
  // resblock 1
  k_convm9<<<400, 256, 0, stream>>>(SKIPH, WB2,        BNS,     nullptr, ZB, T1H, nullptr);
  k_convm9<<<400, 256, 0, stream>>>(T1H,   WB2+WP,     BNS+192, SKIPF,   ZB, T2H, T2F);
  // resblock 2
  k_convm9<<<400, 256, 0, stream>>>(T2H,   WB2+2*WP,   BNS+384, nullptr, ZB, T1H, nullptr);
  k_convm9<<<400, 256, 0, stream>>>(T1H,   WB2+3*WP,   BNS+576, T2F,     ZB, T3H, nullptr);
  k_finm  <<<400, 256, 0, stream>>>(SKIPF, T3H, W8H, b8, (float*)d_out);
}

// Round 26
// 267.803 us; speedup vs baseline: 1.0388x; 1.0003x over previous
//
#include <hip/hip_runtime.h>
#include <hip/hip_bf16.h>

// Problem constants
#define NN 25600      // D*H*W = 16*40*40
#define CC 96
#define NHh 4
#define HDd 24
#define SSLOT 2457600 // NN*CC floats per workspace slot
#define WP 269568     // padded conv weight tensor: 27*96*104 ushorts

typedef unsigned short ushort_t;
typedef float f32x4 __attribute__((ext_vector_type(4)));
typedef short s16x8 __attribute__((ext_vector_type(8)));
typedef _Float16 f16;
typedef f16 h2v __attribute__((ext_vector_type(2)));

__device__ __forceinline__ float LD(const void* p, int i){
  return ((const float*)p)[i];
}
__device__ __forceinline__ float b2f(ushort_t u){ return __uint_as_float(((unsigned)u)<<16); }
__device__ __forceinline__ ushort_t f2b(float f){
  unsigned u = __float_as_uint(f);
  unsigned r = (u + 0x7fffu + ((u>>16)&1u))>>16;
  return (ushort_t)r;
}
__device__ __forceinline__ ushort_t f2h(float f){
  f16 hv = (f16)f;
  return *reinterpret_cast<ushort_t*>(&hv);
}
__device__ __forceinline__ float fdot2(h2v a, h2v b, float c){
#if __has_builtin(__builtin_amdgcn_fdot2)
  return __builtin_amdgcn_fdot2(a, b, c, false);
#else
  return c + (float)a[0]*(float)b[0] + (float)a[1]*(float)b[1];
#endif
}
__device__ __forceinline__ void gl_lds16(const void* g, const void* l){
  __builtin_amdgcn_global_load_lds(
      (const __attribute__((address_space(1))) unsigned*)g,
      (__attribute__((address_space(3))) unsigned*)l, 16, 0, 0);
}

#define NEGINF (-3.0e38f)

// ---------------- MEGA prologue: prepall | rpiT | ln | tab in one launch ------------
__global__ __launch_bounds__(256) void k_mega(
    const void* w0, const void* w1, const void* w2, const void* w3,
    const void* wq, const void* wsr, const void* w8,
    const void* o1w, const void* o1b, const void* o2w, const void* o2b,
    const void* b0, const void* b1, const void* b2bn, const void* b3,
    const void* ltok,
    ushort_t* __restrict__ WB2, ushort_t* __restrict__ WQH,
    ushort_t* __restrict__ WSH, ushort_t* __restrict__ W8H,
    ushort_t* __restrict__ WE, float* __restrict__ EB,
    float* __restrict__ BNS, ushort_t* __restrict__ LTOKT,
    float* __restrict__ ZB,
    const int* __restrict__ rpi, int* __restrict__ rpiT,
    const void* __restrict__ x, const void* __restrict__ nw,
    const void* __restrict__ nb, ushort_t* __restrict__ XNH,
    const void* __restrict__ rct, const void* __restrict__ w1t,
    const void* __restrict__ b1t, const void* __restrict__ w2t,
    const void* __restrict__ b2t, float* __restrict__ TAB)
{
  __shared__ __align__(16) char SMEM[15400];
  int b = blockIdx.x, tid = threadIdx.x;
  if(b < 4212){
    int e = b*256 + tid;
    {
      int t = e/WP, r = e%WP;
      int tap = r/9984, r2 = r%9984, o = r2/104, p = r2%104;
      const void* w = (t==0)? w0 : (t==1)? w1 : (t==2)? w2 : w3;
      WB2[e] = (p<96)? f2b(LD(w, (o*96+p)*27 + tap)) : (ushort_t)0;
    }
    if(e < 36864) WQH[e] = f2b(LD(wq,e));
    if(e < 9216){ WSH[e] = f2b(LD(wsr,e)); W8H[e] = f2b(LD(w8,e)); }
    if(e < 96*192){
      int o = e/192, c2 = e%192;
      float v = 0.f;
      if(o < 48 && c2 < 96)        v = LD(o1w, o*96 + c2);
      else if(o >= 48 && c2 >= 96) v = LD(o2w, (o-48)*96 + (c2-96));
      WE[e] = f2b(v);
      if(c2 == 0) EB[o] = (o<48)? LD(o1b,o) : LD(o2b,o-48);
    }
    if(e < 384){
      int t = e/96, o = e%96;
      const void* bn = (t==0)? b0 : (t==1)? b1 : (t==2)? b2bn : b3;
      float g=LD(bn,o), bb=LD(bn,96+o), mu=LD(bn,192+o), var=LD(bn,288+o);
      float s = g*rsqrtf(var+1e-5f);
      BNS[t*192+o] = s;
      BNS[t*192+96+o] = bb - mu*s;
    }
    if(e < 4096){
      int h = e/1024, r = e%1024, kk = r/32, d = r%32;
      float v = (d<24 && kk<27)? LD(ltok, (h*24+d)*27 + kk) : 0.f;
      LTOKT[e] = f2b(v);
    }
    if(e < 8) ZB[e] = 0.f;
  } else if(b < 4612){
    int* T = (int*)SMEM;                 // [50][65]
    int n0 = (b-4212)*64;
    for(int f=tid; f<3200; f+=256){
      int nl = f/50, p = f%50;
      T[p*65+nl] = rpi[n0*50 + f];
    }
    __syncthreads();
    for(int f=tid; f<3200; f+=256){
      int p = f>>6, nl = f&63;
      rpiT[(size_t)p*NN + n0 + nl] = T[p*65+nl];
    }
  } else if(b < 5012){
    float* reds  = (float*)SMEM;         // [4][64]
    float* redss = reds + 256;           // [4][64]
    ushort_t* OUT = (ushort_t*)(redss + 256); // [64][100]
    int bx = b - 4612;
    int nl = tid&63, cg = tid>>6;
    int n = bx*64 + nl;
    float v[24]; float s=0.f, ss=0.f;
    #pragma unroll
    for(int i=0;i<24;i++){
      float t = LD(x, (cg*24+i)*NN + n) + 1.0f;
      v[i]=t; s+=t; ss+=t*t;
    }
    reds[cg*64+nl]=s; redss[cg*64+nl]=ss;
    __syncthreads();
    float S  = reds[nl]+reds[64+nl]+reds[128+nl]+reds[192+nl];
    float SS = redss[nl]+redss[64+nl]+redss[128+nl]+redss[192+nl];
    float mu = S*(1.0f/CC);
    float inv = rsqrtf(SS*(1.0f/CC) - mu*mu + 1e-5f);
    #pragma unroll
    for(int i=0;i<24;i++){
      int c = cg*24+i;
      OUT[nl*100+c] = f2b((v[i]-mu)*inv*LD(nw,c) + LD(nb,c));
    }
    __syncthreads();
    for(int f=tid; f<3072; f+=256){
      int r = f/48, dp = f%48;
      unsigned pk = (unsigned)OUT[r*100+dp*2] | ((unsigned)OUT[r*100+dp*2+1]<<16);
      *reinterpret_cast<unsigned*>(XNH + (size_t)(bx*64+r)*96 + dp*2) = pk;
    }
  } else {
    float* red = (float*)SMEM;           // [16]
    int tt = b - 5012, j = tid;
    float r0=LD(rct,tt*3), r1=LD(rct,tt*3+1), r2=LD(rct,tt*3+2);
    float hA = r0*LD(w1t,j*3) + r1*LD(w1t,j*3+1) + r2*LD(w1t,j*3+2) + LD(b1t,j);
    hA = fmaxf(hA, 0.f);
    int j2 = j + 256;
    float hB = r0*LD(w1t,j2*3) + r1*LD(w1t,j2*3+1) + r2*LD(w1t,j2*3+2) + LD(b1t,j2);
    hB = fmaxf(hB, 0.f);
    int lane=j&63, wid=j>>6;
    for(int h=0;h<4;h++){
      float v = hA*LD(w2t, h*512+j) + hB*LD(w2t, h*512+j2);
      #pragma unroll
      for(int off=32;off;off>>=1) v += __shfl_down(v, off);
      if(lane==0) red[wid*4+h]=v;
    }
    __syncthreads();
    if(j<4){
      float s = red[j] + red[4+j] + red[8+j] + red[12+j];
      TAB[tt*4+j] = s + LD(b2t,j);
    }
  }
}

// ---------------- K2+K4 fused: qkvv (y=0,1) and sr+gelu (y=2) MFMA GEMMs -----------
__global__ __launch_bounds__(256,2) void k_qkvsr(
    const ushort_t* __restrict__ XNH, const ushort_t* __restrict__ WQH,
    const ushort_t* __restrict__ WSH, const void* __restrict__ srb,
    float* __restrict__ out, ushort_t* __restrict__ KH,
    ushort_t* __restrict__ VH, float* __restrict__ XP2){
  int tid=threadIdx.x, w=tid>>6, lane=tid&63, lan=lane&15, grp=lane>>4;
  int n = blockIdx.x*64 + w*16 + lan;
  const ushort_t* bp = XNH + n*96;
  if(blockIdx.y < 2){
    int ybase = blockIdx.y*192;
    f32x4 acc[12];
    #pragma unroll
    for(int mt=0;mt<12;mt++) acc[mt] = (f32x4)(0.f);
    #pragma unroll
    for(int s=0;s<3;s++){
      s16x8 b = *reinterpret_cast<const s16x8*>(bp + s*32 + grp*8);
      #pragma unroll
      for(int mt=0;mt<12;mt++){
        s16x8 a = *reinterpret_cast<const s16x8*>(WQH + (ybase+mt*16+lan)*96 + s*32 + grp*8);
        acc[mt] = __builtin_amdgcn_mfma_f32_16x16x32_bf16(a, b, acc[mt], 0,0,0);
      }
    }
    #pragma unroll
    for(int mt=0;mt<12;mt++){
      int o0 = ybase + mt*16 + grp*4;
      int sl = o0/96, rr = o0%96, h = rr/24, dd = rr%24;
      f32x4 v = acc[mt];
      if(sl == 3){
        ushort4 pk = { f2h(v[0]), f2h(v[1]), f2h(v[2]), f2h(v[3]) };
        *reinterpret_cast<ushort4*>(VH + ((size_t)h*NN+n)*24 + dd) = pk;
      } else {
        *reinterpret_cast<float4*>(out + sl*SSLOT + ((size_t)h*NN+n)*24 + dd) =
            (float4){v[0],v[1],v[2],v[3]};
        if(sl == 1){
          ushort4 pk = { f2h(v[0]), f2h(v[1]), f2h(v[2]), f2h(v[3]) };
          *reinterpret_cast<ushort4*>(KH + ((size_t)h*NN+n)*24 + dd) = pk;
        }
      }
    }
  } else {
    f32x4 acc[6];
    #pragma unroll
    for(int mt=0;mt<6;mt++) acc[mt] = (f32x4)(0.f);
    #pragma unroll
    for(int s=0;s<3;s++){
      s16x8 b = *reinterpret_cast<const s16x8*>(bp + s*32 + grp*8);
      #pragma unroll
      for(int mt=0;mt<6;mt++){
        s16x8 a = *reinterpret_cast<const s16x8*>(WSH + (mt*16+lan)*96 + s*32 + grp*8);
        acc[mt] = __builtin_amdgcn_mfma_f32_16x16x32_bf16(a, b, acc[mt], 0,0,0);
      }
    }
    #pragma unroll
    for(int mt=0;mt<6;mt++){
      #pragma unroll
      for(int r=0;r<4;r++){
        int o = mt*16 + grp*4 + r;
        float y = acc[mt][r] + LD(srb,o);
        y = 0.5f*y*(1.0f + erff(y*0.70710678118f));
        XP2[o*NN+n] = y;
      }
    }
  }
}

// ---------------- MID1: qsltm (b<400) | pool x4 (b>=400) ----------------
__global__ __launch_bounds__(256) void k_mid1(
    const float* __restrict__ Q, const void* __restrict__ temp,
    const void* __restrict__ sls, const void* __restrict__ qe,
    const ushort_t* __restrict__ LTOKT, const void* __restrict__ lbias,
    float* __restrict__ QS, ushort_t* __restrict__ LTH,
    const float* __restrict__ XP2, float* __restrict__ pooled)
{
  __shared__ ushort_t QL[4][64][32];   // 16 KB
  int b = blockIdx.x, tid = threadIdx.x;
  if(b < 400){
    int h = tid>>6, nl = tid&63;
    int n0 = b*64, n = n0 + nl;
    const float* qr = Q + ((size_t)h*NN+n)*24;
    float qv[24]; float ssum=0.f;
    #pragma unroll
    for(int d=0;d<24;d++){ qv[d]=qr[d]; ssum+=qv[d]*qv[d]; }
    float inv = 1.0f/fmaxf(sqrtf(ssum), 1e-12f);
    float t = LD(temp,h);
    float sp = log1pf(expf(t)) * LD(sls,0);
    float* qs = QS + ((size_t)h*NN+n)*24;
    #pragma unroll
    for(int d=0;d<24;d+=2){
      float q0 = qv[d]*inv, q1 = qv[d+1]*inv;
      unsigned pk = (unsigned)f2b(q0) | ((unsigned)f2b(q1)<<16);
      *reinterpret_cast<unsigned*>(&QL[h][nl][d]) = pk;
      qs[d]   = (q0 + LD(qe, h*24+d))*sp;
      qs[d+1] = (q1 + LD(qe, h*24+d+1))*sp;
    }
    *reinterpret_cast<unsigned*>(&QL[h][nl][24]) = 0;
    *reinterpret_cast<unsigned*>(&QL[h][nl][26]) = 0;
    *reinterpret_cast<unsigned*>(&QL[h][nl][28]) = 0;
    *reinterpret_cast<unsigned*>(&QL[h][nl][30]) = 0;
    __syncthreads();
    int lane=tid&63, lan=lane&15, grp=lane>>4;
    f32x4 acc[4][2];
    #pragma unroll
    for(int j=0;j<4;j++)
      #pragma unroll
      for(int tt=0;tt<2;tt++) acc[j][tt] = (f32x4)(0.f);
    #pragma unroll
    for(int j=0;j<4;j++){
      s16x8 bb = *reinterpret_cast<const s16x8*>(&QL[h][j*16+lan][grp*8]);
      #pragma unroll
      for(int tt=0;tt<2;tt++){
        s16x8 a = *reinterpret_cast<const s16x8*>(LTOKT + h*1024 + (tt*16+lan)*32 + grp*8);
        acc[j][tt] = __builtin_amdgcn_mfma_f32_16x16x32_bf16(a, bb, acc[j][tt], 0,0,0);
      }
    }
    #pragma unroll
    for(int j=0;j<4;j++){
      int nn = n0 + j*16 + lan;
      #pragma unroll
      for(int tt=0;tt<2;tt++){
        int k0 = tt*16 + grp*4;
        if(k0 < 28){
          ushort4 pk;
          ushort_t* pp = reinterpret_cast<ushort_t*>(&pk);
          #pragma unroll
          for(int r=0;r<4;r++){
            int k = k0+r;
            float v = acc[j][tt][r] + ((k<27)? LD(lbias, h*27+k) : 0.f);
            pp[r] = f2h(v);
          }
          *reinterpret_cast<ushort4*>(LTH + ((size_t)h*NN+nn)*28 + k0) = pk;
        }
      }
    }
  } else {
    int w = tid>>6, lane = tid&63;
    int pb = (b-400)*4 + w;              // [0,4800)
    int c = pb % CC, p = pb / CC;
    int ph = p/10, pw = (p%10)/2, pd = p%2;
    float s = 0.f;
    for(int t=lane; t<512; t+=64){
      int i=t>>6, j=(t>>3)&7, k=t&7;
      int m = (ph*8+i)*640 + (pw*8+j)*16 + (pd*8+k);
      s += XP2[c*NN+m];
    }
    #pragma unroll
    for(int off=32;off;off>>=1) s += __shfl_down(s, off);
    if(lane==0) pooled[p*CC+c] = s*(1.0f/512.0f);
  }
}

// ---------------- MID2: LN(pooled) + kv + inlined kpn -> KPNH/VPH f16 ---------------
__global__ void k_mid2(const float* __restrict__ pooled, const void* __restrict__ ew,
                       const void* __restrict__ eb, const void* __restrict__ wkv,
                       ushort_t* __restrict__ KPNH, ushort_t* __restrict__ VPH){
  __shared__ float row[96], lnr[96], st[2], kk[96];
  int p = blockIdx.x, t = threadIdx.x;
  if(t<96) row[t] = pooled[p*96+t];
  __syncthreads();
  if(t==0){
    float s=0.f, ss=0.f;
    for(int c=0;c<96;c++){ float v=row[c]; s+=v; ss+=v*v; }
    float mu=s*(1.0f/96.0f);
    float var=ss*(1.0f/96.0f)-mu*mu;
    st[0]=mu; st[1]=rsqrtf(var+1e-5f);
  }
  __syncthreads();
  if(t<96) lnr[t] = (row[t]-st[0])*st[1]*LD(ew,t) + LD(eb,t);
  __syncthreads();
  if(t<192){
    float a=0.f;
    for(int c=0;c<96;c++) a += LD(wkv, t*96+c)*lnr[c];
    int g=t/24, d=t%24;
    if(g<4) kk[t]=a;
    else    VPH[((g-4)*50+p)*24+d] = f2h(a);
  }
  __syncthreads();
  if(t<96){
    int g=t/24, d=t%24;
    float ss=0.f;
    #pragma unroll
    for(int e=0;e<24;e++){ float v=kk[g*24+e]; ss+=v*v; }
    float inv = 1.0f/fmaxf(sqrtf(ss),1e-12f);
    KPNH[((g*50+p)*24)+d] = f2h(kk[t]*inv);
  }
}

// ---------------- BIG: cascore3 FIRST (b<64) | attn6 (b in [64,464)) ----------------
// attn gathers (rpiT -> TAB) split into batched passes: all index loads in flight,
// then all table loads, then dot-product accumulation.
__global__ __launch_bounds__(512) void k_big(
    const float* __restrict__ QS, const ushort_t* __restrict__ KH,
    const ushort_t* __restrict__ VH,
    const ushort_t* __restrict__ KPNH, const ushort_t* __restrict__ VPH,
    const float* __restrict__ TAB, const int* __restrict__ rpiT,
    const void* __restrict__ rbl, const ushort_t* __restrict__ LTH,
    ushort_t* __restrict__ XH,
    const float* __restrict__ Q, const float* __restrict__ K,
    float* __restrict__ PAR)
{
  __shared__ ushort_t KVH[2][600*26];   // 62.4 KB (aliased by cascore3's reduce)
  int bb = blockIdx.x, tid = threadIdx.x;
  if(bb >= 64){
    int bb2 = bb - 64;
    int tile = bb2 % 100, h = bb2 / 100;
    int g = tile/25, sp = tile%25, hg = sp/5, wg = sp%5;
    int role = tid>>8, q = tid & 255;
    int wq = q>>6, l = q&63;
    int hy = l>>3, wx = l&7;
    int d0 = g*4 + wq;
    int h0 = hg*8+hy, w0 = wg*8+wx;
    int n = d0*1600 + h0*40 + w0;

    const ushort_t* KHh = KH + (size_t)h*NN*24;
    const ushort_t* VHh = VH + (size_t)h*NN*24;
    for(int f=tid; f<3600; f+=512){
      int t = f/1800, rem = f%1800, row = rem/3, qq = rem%3;
      int dr = row/100, yr = (row%100)/10, xr = row%10;
      int zc = min(max(g*4+dr-1,0),15), yc = min(max(hg*8+yr-1,0),39), xc = min(max(wg*8+xr-1,0),39);
      const ushort_t* src = (t? VHh : KHh) + (size_t)(zc*1600+yc*40+xc)*24 + qq*8;
      const unsigned* s32 = reinterpret_cast<const unsigned*>(src);
      unsigned a0=s32[0], a1=s32[1], a2=s32[2], a3=s32[3];
      unsigned* d32 = reinterpret_cast<unsigned*>(&KVH[t][row*26 + qq*8]);
      d32[0]=a0; d32[1]=a1; d32[2]=a2; d32[3]=a3;
    }

    h2v qp[12];
    {
      const float* qsp = QS + ((size_t)h*NN+n)*24;
      #pragma unroll
      for(int d=0; d<24; d+=4){
        float4 a = *reinterpret_cast<const float4*>(qsp+d);
        qp[d/2]   = (h2v){ (f16)a.x, (f16)a.y };
        qp[d/2+1] = (h2v){ (f16)a.z, (f16)a.w };
      }
    }
    __syncthreads();

    float m_r, s_r;
    h2v accA[12], accT[12];
    #pragma unroll
    for(int j=0;j<12;j++){ accA[j]=(h2v){(f16)0.f,(f16)0.f}; accT[j]=(h2v){(f16)0.f,(f16)0.f}; }

    const h2v* kph = reinterpret_cast<const h2v*>(KPNH) + (size_t)h*50*12;
    const h2v* vph = reinterpret_cast<const h2v*>(VPH)  + (size_t)h*50*12;

    if(role==0){
      float av[39]; unsigned okm=0;
      // batched gather: indices, then table values
      int idx[12];
      #pragma unroll
      for(int p=0;p<12;p++) idx[p] = rpiT[(size_t)p*NN+n];
      #pragma unroll
      for(int p=0;p<12;p++) av[27+p] = TAB[idx[p]*4 + h];
      #pragma unroll
      for(int k=0;k<27;k++){
        int kz=k/9, ky=(k%9)/3, kx=k%3;
        bool ok = (unsigned)(d0+kz-1)<16u && (unsigned)(h0+ky-1)<40u && (unsigned)(w0+kx-1)<40u;
        float sc = NEGINF;
        if(ok){
          okm |= 1u<<k;
          const h2v* kr = reinterpret_cast<const h2v*>(
              &KVH[0][((wq+kz)*100 + (hy+ky)*10 + (wx+kx))*26]);
          sc = LD(rbl, h*27+k);
          #pragma unroll
          for(int j=0;j<12;j++) sc = fdot2(kr[j], qp[j], sc);
        }
        av[k]=sc;
      }
      #pragma unroll
      for(int p=0;p<12;p++){
        float sc = av[27+p];
        const h2v* kr = kph + p*12;
        #pragma unroll
        for(int j=0;j<12;j++) sc = fdot2(kr[j], qp[j], sc);
        av[27+p]=sc;
      }
      float m = av[0];
      #pragma unroll
      for(int k=1;k<39;k++) m = fmaxf(m, av[k]);
      const f16* ltp = reinterpret_cast<const f16*>(LTH) + ((size_t)h*NN+n)*28;
      float s = 0.f;
      #pragma unroll
      for(int k=0;k<27;k++){
        if(okm>>k & 1u){
          int kz=k/9, ky=(k%9)/3, kx=k%3;
          float e = __expf(av[k]-m);
          s += e;
          float ltv = (float)ltp[k];
          h2v we = { (f16)e, (f16)e };
          h2v wt = { (f16)ltv, (f16)ltv };
          const h2v* vr = reinterpret_cast<const h2v*>(
              &KVH[1][((wq+kz)*100 + (hy+ky)*10 + (wx+kx))*26]);
          #pragma unroll
          for(int j=0;j<12;j++){
            accA[j] = vr[j]*we + accA[j];
            accT[j] = vr[j]*wt + accT[j];
          }
        }
      }
      #pragma unroll
      for(int p=0;p<12;p++){
        float e = __expf(av[27+p]-m);
        s += e;
        h2v we = { (f16)e, (f16)e };
        const h2v* vr = vph + p*12;
        #pragma unroll
        for(int j=0;j<12;j++) accA[j] = vr[j]*we + accA[j];
      }
      m_r = m; s_r = s;
    } else {
      float av[38];
      // batched gather: all 38 indices in flight, then all 38 table loads
      int idx[38];
      #pragma unroll
      for(int p=0;p<38;p++) idx[p] = rpiT[(size_t)(p+12)*NN+n];
      #pragma unroll
      for(int p=0;p<38;p++) av[p] = TAB[idx[p]*4 + h];
      #pragma unroll
      for(int p=0;p<38;p++){
        float sc = av[p];
        const h2v* kr = kph + (p+12)*12;
        #pragma unroll
        for(int j=0;j<12;j++) sc = fdot2(kr[j], qp[j], sc);
        av[p]=sc;
      }
      float m = av[0];
      #pragma unroll
      for(int p=1;p<38;p++) m = fmaxf(m, av[p]);
      float s = 0.f;
      #pragma unroll
      for(int p=0;p<38;p++){
        float e = __expf(av[p]-m);
        s += e;
        h2v we = { (f16)e, (f16)e };
        const h2v* vr = vph + (p+12)*12;
        #pragma unroll
        for(int j=0;j<12;j++) accA[j] = vr[j]*we + accA[j];
      }
      m_r = m; s_r = s;
    }
    __syncthreads();

    float* PP = (float*)&KVH[0][0];
    if(role==1){
      PP[q*15+0] = m_r;
      PP[q*15+1] = s_r;
      #pragma unroll
      for(int j=0;j<12;j++){
        h2v a = accA[j];
        PP[q*15+2+j] = __uint_as_float(*reinterpret_cast<unsigned*>(&a));
      }
    }
    __syncthreads();

    float* TRF = (float*)&KVH[0][0] + 4096;
    if(role==0){
      float mp = PP[q*15+0], sp2 = PP[q*15+1];
      float m = fmaxf(m_r, mp);
      float a = __expf(m_r - m), b = __expf(mp - m);
      float inv = 1.0f/(a*s_r + b*sp2);
      #pragma unroll
      for(int j=0;j<12;j++){
        unsigned pb = __float_as_uint(PP[q*15+2+j]);
        h2v ap = *reinterpret_cast<h2v*>(&pb);
        float v0 = (a*(float)accA[j][0] + b*(float)ap[0])*inv + (float)accT[j][0];
        float v1 = (a*(float)accA[j][1] + b*(float)ap[1])*inv + (float)accT[j][1];
        TRF[q*25 + 2*j]   = v0;
        TRF[q*25 + 2*j+1] = v1;
      }
    }
    __syncthreads();

    for(int f=tid; f<3072; f+=512){
      int q2 = f/12, dp = f%12;
      int w2 = q2>>6, l2 = q2&63;
      int n2 = (g*4+w2)*1600 + (hg*8+(l2>>3))*40 + (wg*8+(l2&7));
      float v0 = TRF[q2*25+dp*2], v1 = TRF[q2*25+dp*2+1];
      unsigned pk = (unsigned)f2b(v0) | ((unsigned)f2b(v1)<<16);
      *reinterpret_cast<unsigned*>(XH + (size_t)n2*192 + h*24 + dp*2) = pk;
    }
  } else {
    // cascore3: register-tiled QtK. 64 blocks: (h, chunk16). Q,K read exactly once.
    float* WRED = (float*)&KVH[0][0];    // [8 waves][36 lanes][25] = 28.8 KB
    int b2 = bb;                         // [0,64)
    int h = b2 >> 4, chunk = b2 & 15;
    int wv = tid >> 6, lane = tid & 63;
    int n0 = chunk*1600 + wv*200;
    const float* Qh = Q + (size_t)h*NN*24;
    const float* Kh = K + (size_t)h*NN*24;
    int r = lane/6, cgl = lane%6;
    bool act = lane < 36;
    int d1 = r*4, d2 = cgl*4;
    float accm[4][4];
    #pragma unroll
    for(int i=0;i<4;i++)
      #pragma unroll
      for(int j=0;j<4;j++) accm[i][j]=0.f;
    float qss4[4] = {0.f,0.f,0.f,0.f}, kss4[4] = {0.f,0.f,0.f,0.f};
    if(act){
      #pragma unroll 4
      for(int i=0;i<200;i++){
        int n = n0 + i;
        float4 q4 = *reinterpret_cast<const float4*>(Qh + (size_t)n*24 + d1);
        float4 k4 = *reinterpret_cast<const float4*>(Kh + (size_t)n*24 + d2);
        float qa[4] = {q4.x,q4.y,q4.z,q4.w};
        float ka[4] = {k4.x,k4.y,k4.z,k4.w};
        #pragma unroll
        for(int i2=0;i2<4;i2++)
          #pragma unroll
          for(int j=0;j<4;j++) accm[i2][j] += qa[i2]*ka[j];
        #pragma unroll
        for(int e=0;e<4;e++){ qss4[e]+=qa[e]*qa[e]; kss4[e]+=ka[e]*ka[e]; }
      }
      float* wp = WRED + (wv*36 + lane)*25;
      #pragma unroll
      for(int i=0;i<4;i++)
        #pragma unroll
        for(int j=0;j<4;j++) wp[i*4+j] = accm[i][j];
      if(r == cgl){
        #pragma unroll
        for(int e=0;e<4;e++){ wp[16+e]=qss4[e]; wp[20+e]=kss4[e]; }
      }
    }
    __syncthreads();
    for(int c=tid; c<624; c+=512){
      float s = 0.f;
      if(c < 576){
        int d1o = c/24, d2o = c%24;
        int li = (d1o>>2)*6 + (d2o>>2);
        int sl = (d1o&3)*4 + (d2o&3);
        #pragma unroll
        for(int w8=0;w8<8;w8++) s += WRED[(w8*36+li)*25+sl];
        PAR[((size_t)chunk*96 + h*24 + d1o)*26 + d2o] = s;
      } else {
        int cc = c - 576;               // [0,48)
        int d = cc % 24, isk = cc / 24;
        int li = (d>>2)*7;              // diagonal lane
        int sl = 16 + isk*4 + (d&3);
        #pragma unroll
        for(int w8=0;w8<8;w8++) s += WRED[(w8*36+li)*25+sl];
        PAR[((size_t)chunk*96 + h*24 + d)*26 + 24 + isk] = s;
      }
    }
  }
}

// ---------------- CAEP: casm2 recomputed in-block (16 chunks) + caout2 --------------
__global__ __launch_bounds__(256) void k_caep(
    const float* __restrict__ PAR, const void* __restrict__ t2,
    const float* __restrict__ VCA, ushort_t* __restrict__ XH){
  __shared__ float A[2304];
  __shared__ float kinv_s[96];
  int t = threadIdx.x;
  float S[24]; float qi=0.f;
  int hh = (t<96)? t/24 : 0;
  if(t<96){
    float qss=0.f, kss=0.f;
    #pragma unroll
    for(int e=0;e<24;e++) S[e]=0.f;
    for(int c=0;c<16;c++){
      const float* pp = PAR + ((size_t)c*96+t)*26;
      #pragma unroll
      for(int e=0;e<24;e++) S[e] += pp[e];
      qss += pp[24]; kss += pp[25];
    }
    qi = 1.0f/fmaxf(sqrtf(qss),1e-12f);
    kinv_s[t] = 1.0f/fmaxf(sqrtf(kss),1e-12f);
  }
  __syncthreads();
  if(t<96){
    float tv = LD(t2,hh);
    float v[24]; float m = NEGINF;
    #pragma unroll
    for(int e=0;e<24;e++){
      v[e] = S[e]*qi*kinv_s[hh*24+e]*tv;
      m = fmaxf(m, v[e]);
    }
    float s=0.f;
    #pragma unroll
    for(int e=0;e<24;e++){ v[e]=__expf(v[e]-m); s+=v[e]; }
    float inv=1.0f/s;
    #pragma unroll
    for(int e=0;e<24;e++) A[t*24+e] = v[e]*inv;
  }
  __syncthreads();
  int h = t>>6, l = t&63;
  int n = blockIdx.x*64 + l;
  float vr[24];
  const float* vp = VCA + ((size_t)h*NN+n)*24;
  #pragma unroll
  for(int e=0;e<24;e+=4){
    float4 v = *reinterpret_cast<const float4*>(vp+e);
    vr[e]=v.x; vr[e+1]=v.y; vr[e+2]=v.z; vr[e+3]=v.w;
  }
  float o[24];
  #pragma unroll
  for(int d=0;d<24;d++){
    float a=0.f;
    const float* ar = A + (h*24+d)*24;
    #pragma unroll
    for(int e=0;e<24;e++) a += ar[e]*vr[e];
    o[d]=a;
  }
  #pragma unroll
  for(int d=0;d<24;d+=2){
    unsigned pk = (unsigned)f2b(o[d]) | ((unsigned)f2b(o[d+1])<<16);
    *reinterpret_cast<unsigned*>(XH + (size_t)n*192 + 96 + h*24 + d) = pk;
  }
}

// ---------------- K9: epa MFMA (K=192 block-diagonal) + x+1+gamma fused ----------
__global__ __launch_bounds__(256,2) void k_epam(
    const ushort_t* __restrict__ XH, const ushort_t* __restrict__ WE,
    const float* __restrict__ EB, const void* __restrict__ x,
    const void* __restrict__ gamma,
    float* __restrict__ SKIPF, ushort_t* __restrict__ SKIPH){
  int tid=threadIdx.x, w=tid>>6, lane=tid&63, lan=lane&15, grp=lane>>4;
  int n = blockIdx.x*64 + w*16 + lan;
  const ushort_t* bp = XH + (size_t)n*192;
  f32x4 acc[6];
  #pragma unroll
  for(int mt=0;mt<6;mt++) acc[mt] = (f32x4)(0.f);
  #pragma unroll
  for(int s=0;s<6;s++){
    s16x8 b = *reinterpret_cast<const s16x8*>(bp + s*32 + grp*8);
    #pragma unroll
    for(int mt=0;mt<6;mt++){
      s16x8 a = *reinterpret_cast<const s16x8*>(WE + (mt*16+lan)*192 + s*32 + grp*8);
      acc[mt] = __builtin_amdgcn_mfma_f32_16x16x32_bf16(a, b, acc[mt], 0,0,0);
    }
  }
  #pragma unroll
  for(int mt=0;mt<6;mt++){
    #pragma unroll
    for(int r=0;r<4;r++){
      int o = mt*16 + grp*4 + r;
      float e = acc[mt][r] + EB[o];
      float v = LD(x, o*NN+n) + 1.0f + LD(gamma,o)*e;
      SKIPF[(size_t)n*96+o] = v;
      SKIPH[(size_t)n*96+o] = f2b(v);
    }
  }
}

// ---------------- K10: conv3x3x3, async gl_lds + 32nx48out wave tiling --------------
__global__ __launch_bounds__(256,2) void k_convm9(
    const ushort_t* __restrict__ IN, const ushort_t* __restrict__ WB2,
    const float* __restrict__ BNS, const float* __restrict__ resf,
    const float* __restrict__ ZB,
    ushort_t* __restrict__ outh, float* __restrict__ outf)
{
  __shared__ ushort_t BUF[2][16640];
  int tid = threadIdx.x;
  int w = tid>>6, lane = tid&63;
  int lan = lane&15, grp = lane>>4;
  int ng = w&1, og = w>>1;
  int bs = (blockIdx.x&7)*50 + (blockIdx.x>>3);
  int n0 = bs*64;

  auto STAGE = [&](int tap, ushort_t* buf){
    int dx=tap/9-1, dy=(tap%9)/3-1, dz=tap%3-1;
    int off = dx*640 + dy*16 + dz;
    const ushort_t* wsrc = WB2 + tap*9984;
    #pragma unroll
    for(int i=0;i<9;i++){
      int cb = i*256 + w*64;
      if(cb >= 2080) break;
      int c = cb + lane;
      const void* src;
      if(c < 1248){
        src = wsrc + c*8;
      } else {
        int c2 = c - 1248;
        int r = c2/13, p = c2%13;
        int nn = n0 + r;
        int X = nn/640, rr2 = nn%640, Y = rr2/16, Z = nn&15;
        bool ok = (p<12) && (unsigned)(X+dx)<40u && (unsigned)(Y+dy)<40u && (unsigned)(Z+dz)<16u;
        src = ok ? (const void*)(IN + (size_t)(nn+off)*96 + p*8) : (const void*)ZB;
      }
      if(c < 2080) gl_lds16(src, buf + cb*8);
    }
  };

  f32x4 acc[2][3];
  #pragma unroll
  for(int nt=0;nt<2;nt++)
    #pragma unroll
    for(int mt=0;mt<3;mt++) acc[nt][mt] = (f32x4)(0.f);

  STAGE(0, BUF[0]);
  asm volatile("s_waitcnt vmcnt(0)" ::: "memory");
  __builtin_amdgcn_s_barrier();

  for(int tap=0; tap<27; ++tap){
    if(tap<26){
      STAGE(tap+1, BUF[(tap+1)&1]);
      asm volatile("s_waitcnt vmcnt(8)" ::: "memory");
    } else {
      asm volatile("s_waitcnt vmcnt(0)" ::: "memory");
    }
    __builtin_amdgcn_s_barrier();
    __builtin_amdgcn_sched_barrier(0);
    const ushort_t* Ab = BUF[tap&1];
    const ushort_t* Bb = Ab + 9984;
    #pragma unroll
    for(int s=0;s<3;s++){
      s16x8 b0 = *reinterpret_cast<const s16x8*>(Bb + (ng*32 +      lan)*104 + s*32 + grp*8);
      s16x8 b1 = *reinterpret_cast<const s16x8*>(Bb + (ng*32 + 16 + lan)*104 + s*32 + grp*8);
      #pragma unroll
      for(int mt=0;mt<3;mt++){
        s16x8 a = *reinterpret_cast<const s16x8*>(Ab + (og*48 + mt*16 + lan)*104 + s*32 + grp*8);
        acc[0][mt] = __builtin_amdgcn_mfma_f32_16x16x32_bf16(a, b0, acc[0][mt], 0,0,0);
        acc[1][mt] = __builtin_amdgcn_mfma_f32_16x16x32_bf16(a, b1, acc[1][mt], 0,0,0);
      }
    }
    __builtin_amdgcn_s_barrier();
  }

  float* TR = (float*)&BUF[0][0];
  #pragma unroll
  for(int nt=0;nt<2;nt++){
    int nl = ng*32 + nt*16 + lan;
    #pragma unroll
    for(int mt=0;mt<3;mt++){
      int ob = og*48 + mt*16 + grp*4;
      float4 vv;
      vv.x = acc[nt][mt][0]*BNS[ob+0] + BNS[96+ob+0];
      vv.y = acc[nt][mt][1]*BNS[ob+1] + BNS[96+ob+1];
      vv.z = acc[nt][mt][2]*BNS[ob+2] + BNS[96+ob+2];
      vv.w = acc[nt][mt][3]*BNS[ob+3] + BNS[96+ob+3];
      *reinterpret_cast<float4*>(TR + nl*100 + ob) = vv;
    }
  }
  __syncthreads();
  for(int f=tid; f<3072; f+=256){
    int r = f/48, cp = f%48;
    int n = n0 + r;
    float v0 = TR[r*100+cp*2], v1 = TR[r*100+cp*2+1];
    if(resf){ v0 += resf[(size_t)n*96+cp*2]; v1 += resf[(size_t)n*96+cp*2+1]; }
    v0 = (v0>=0.f)? v0 : 0.01f*v0;
    v1 = (v1>=0.f)? v1 : 0.01f*v1;
    unsigned pk = (unsigned)f2b(v0) | ((unsigned)f2b(v1)<<16);
    *reinterpret_cast<unsigned*>(outh + (size_t)n*96 + cp*2) = pk;
    if(outf){
      float2 fo; fo.x=v0; fo.y=v1;
      *reinterpret_cast<float2*>(outf + (size_t)n*96 + cp*2) = fo;
    }
  }
}

// ---------------- K11: MFMA final ----------------
__global__ __launch_bounds__(256,2) void k_finm(
    const float* __restrict__ SKIPF, const ushort_t* __restrict__ T3H,
    const ushort_t* __restrict__ W8H, const void* __restrict__ b,
    float* __restrict__ out){
  int tid=threadIdx.x, w=tid>>6, lane=tid&63, lan=lane&15, grp=lane>>4;
  int n = blockIdx.x*64 + w*16 + lan;
  const ushort_t* bp = T3H + n*96;
  f32x4 acc[6];
  #pragma unroll
  for(int mt=0;mt<6;mt++) acc[mt] = (f32x4)(0.f);
  #pragma unroll
  for(int s=0;s<3;s++){
    s16x8 bb = *reinterpret_cast<const s16x8*>(bp + s*32 + grp*8);
    #pragma unroll
    for(int mt=0;mt<6;mt++){
      s16x8 a = *reinterpret_cast<const s16x8*>(W8H + (mt*16+lan)*96 + s*32 + grp*8);
      acc[mt] = __builtin_amdgcn_mfma_f32_16x16x32_bf16(a, bb, acc[mt], 0,0,0);
    }
  }
  #pragma unroll
  for(int mt=0;mt<6;mt++){
    #pragma unroll
    for(int r=0;r<4;r++){
      int o = mt*16 + grp*4 + r;
      out[o*NN+n] = SKIPF[(size_t)n*96+o] + acc[mt][r] + LD(b,o);
    }
  }
}

extern "C" void kernel_launch(void* const* d_in, const int* in_sizes, int n_in,
                              void* d_out, int out_size, void* d_ws, size_t ws_size,
                              hipStream_t stream){
  const void* x     = d_in[0];
  const int*  rpi   = (const int*)d_in[1];
  const void* rct   = d_in[2];
  const void* sls   = d_in[3];
  const void* nw    = d_in[4];
  const void* nb    = d_in[5];
  const void* gamma = d_in[6];
  const void* wqkvv = d_in[7];
  const void* temp  = d_in[8];
  const void* temp2 = d_in[9];
  const void* qe    = d_in[10];
  const void* rbl   = d_in[11];
  const void* ltok  = d_in[12];
  const void* lbias = d_in[13];
  const void* srw   = d_in[14];
  const void* srb   = d_in[15];
  const void* epaw  = d_in[16];
  const void* epab  = d_in[17];
  const void* wkv   = d_in[18];
  const void* c1w   = d_in[19];
  const void* c1b   = d_in[20];
  const void* c2w   = d_in[21];
  const void* c2b   = d_in[22];
  const void* o1w   = d_in[23];
  const void* o1b   = d_in[24];
  const void* o2w   = d_in[25];
  const void* o2b   = d_in[26];
  const void* w51a  = d_in[27];
  const void* bn51a = d_in[28];
  const void* w51b  = d_in[29];
  const void* bn51b = d_in[30];
  const void* w52a  = d_in[31];
  const void* bn52a = d_in[32];
  const void* w52b  = d_in[33];
  const void* bn52b = d_in[34];
  const void* w8    = d_in[35];
  const void* b8    = d_in[36];

  float* ws = (float*)d_ws;
  const size_t S = SSLOT;
  ushort_t* XNH = (ushort_t*)ws;
  float* SKIPF = ws;
  float* Q     = ws + 1*S;
  float* Kb    = ws + 2*S;
  float* T2F   = ws + 2*S;
  float* VCA   = ws + 3*S;
  ushort_t* KH = (ushort_t*)(ws + 4*S);
  ushort_t* VH = KH + SSLOT;
  float* QS    = ws + 6*S;
  ushort_t* XH = (ushort_t*)(ws + 7*S);
  int*   rpiT  = (int*)(ws + 8*S);
  float* XP2   = ws + 7*S;
  ushort_t* SKIPH = (ushort_t*)(ws + 4*S);
  ushort_t* T1H   = SKIPH + SSLOT;
  ushort_t* T2H   = (ushort_t*)(ws + 5*S);
  ushort_t* T3H   = T2H + SSLOT;
  float* SM  = ws + 9*S;
  float* pooled = SM;            // 4800
  float* TAB    = SM + 19200;    // 16384
  ushort_t* WB2 = (ushort_t*)(SM + 40960);   // 4*269568 ushorts
  float* BNS    = SM + 40960 + 539136;       // 768
  ushort_t* WQH = (ushort_t*)(BNS + 768);    // 36864 ushorts
  ushort_t* WSH = WQH + 36864;               // 9216 ushorts
  ushort_t* W8H = WSH + 9216;                // 9216 ushorts
  ushort_t* WE  = W8H + 9216;                // 18432 ushorts
  float* EB     = BNS + 768 + 18432 + 4608 + 4608 + 9216; // 96
  float* PAR    = EB + 96;                   // 16*96*26 = 39936
  ushort_t* KPNH = (ushort_t*)(PAR + 39936); // 4800 ushorts
  ushort_t* VPH  = KPNH + 4800;              // 4800 ushorts
  ushort_t* LTOKT= VPH + 4800;               // 4096 ushorts
  ushort_t* LTH  = LTOKT + 4096;             // 2867200 ushorts
  float* ZB      = (float*)(LTH + 2867200);  // 8 floats

  k_mega  <<<9108, 256, 0, stream>>>(w51a, w51b, w52a, w52b, wqkvv, srw, w8,
                                     o1w, o1b, o2w, o2b,
                                     bn51a, bn51b, bn52a, bn52b, ltok,
                                     WB2, WQH, WSH, W8H, WE, EB, BNS, LTOKT, ZB,
                                     rpi, rpiT,
                                     x, nw, nb, XNH,
                                     rct, c1w, c1b, c2w, c2b, TAB);
  k_qkvsr <<<dim3(400,3), 256, 0, stream>>>(XNH, WQH, WSH, srb, Q, KH, VH, XP2);
  k_mid1  <<<1600, 256, 0, stream>>>(Q, temp, sls, qe, LTOKT, lbias, QS, LTH,
                                     XP2, pooled);
  k_mid2  <<<50,   256, 0, stream>>>(pooled, epaw, epab, wkv, KPNH, VPH);
  k_big   <<<464,  512, 0, stream>>>(QS, KH, VH, KPNH, VPH, TAB, rpiT,
                                     rbl, LTH, XH, Q, Kb, PAR);
  k_caep  <<<400,  256, 0, stream>>>(PAR, temp2, VCA, XH);
  k_epam  <<<400,  256, 0, stream>>>(XH, WE, EB, x, gamma, SKIPF, SKIPH);
  // resblock 1
  k_convm9<<<400, 256, 0, stream>>>(SKIPH, WB2,        BNS,     nullptr, ZB, T1H, nullptr);
  k_convm9<<<400, 256, 0, stream>>>(T1H,   WB2+WP,     BNS+192, SKIPF,   ZB, T2H, T2F);
  // resblock 2
  k_convm9<<<400, 256, 0, stream>>>(T2H,   WB2+2*WP,   BNS+384, nullptr, ZB, T1H, nullptr);
  k_convm9<<<400, 256, 0, stream>>>(T1H,   WB2+3*WP,   BNS+576, T2F,     ZB, T3H, nullptr);
  k_finm  <<<400, 256, 0, stream>>>(SKIPF, T3H, W8H, b8, (float*)d_out);
}